// Round 3
// baseline (1380.011 us; speedup 1.0000x reference)
//
#include <hip/hip_runtime.h>
#include <hip/hip_bf16.h>
#include <math.h>

#define NPB 65536   // pixels per batch (256*256)
#define BATCH 2

typedef unsigned short u16;
typedef __attribute__((ext_vector_type(8))) short short8;
typedef __attribute__((ext_vector_type(4))) float f32x4;

__device__ __forceinline__ float bf2f(u16 u) {
  union { unsigned u; float f; } v; v.u = ((unsigned)u) << 16; return v.f;
}
__device__ __forceinline__ u16 f2bf(float f) {
  union { float f; unsigned u; } v; v.f = f;
  unsigned r = v.u + 0x7FFFu + ((v.u >> 16) & 1u);
  return (u16)(r >> 16);
}
__device__ __forceinline__ unsigned pk2(float a, float b) {
  return (unsigned)f2bf(a) | ((unsigned)f2bf(b) << 16);
}
__device__ __forceinline__ f32x4 mm(short8 a, short8 b, f32x4 c) {
  return __builtin_amdgcn_mfma_f32_16x16x32_bf16(a, b, c, 0, 0, 0);
}
// Build an A-fragment from an f32 weight matrix. row<0 or k>=kval -> 0.
__device__ __forceinline__ short8 afrag(const float* W, int ld, int row, int k0, int kval) {
  short8 r;
#pragma unroll
  for (int j = 0; j < 8; ++j) {
    float v = 0.f;
    if (row >= 0 && (k0 + j) < kval) v = W[(size_t)row * ld + k0 + j];
    r[j] = (short)f2bf(v);
  }
  return r;
}
__device__ __forceinline__ void st4(u16* p, f32x4 c) {
  uint2 v; v.x = pk2(c[0], c[1]); v.y = pk2(c[2], c[3]);
  *reinterpret_cast<uint2*>(p) = v;
}

// ---------------- K1: LN1, channel-major f32 -> pixel-major bf16 [n][64]
__global__ __launch_bounds__(256, 4) void k_ln1(
    const float* __restrict__ x, const float* __restrict__ n1w,
    const float* __restrict__ n1b, u16* __restrict__ Y1)
{
  const int n = blockIdx.x * 256 + threadIdx.x;
  const int b = blockIdx.y;
  const float* xb = x + ((size_t)b * 64) * NPB + n;
  float y[64];
  float mu = 0.f;
#pragma unroll
  for (int c = 0; c < 64; ++c) { y[c] = xb[(size_t)c * NPB]; mu += y[c]; }
  mu *= (1.f / 64.f);
  float var = 0.f;
#pragma unroll
  for (int c = 0; c < 64; ++c) { float d = y[c] - mu; var = fmaf(d, d, var); }
  const float rstd = rsqrtf(var * (1.f / 64.f) + 1e-5f);
#pragma unroll
  for (int c = 0; c < 64; ++c) y[c] = (y[c] - mu) * rstd * n1w[c] + n1b[c];
  u16* dst = Y1 + ((size_t)(b * NPB) + n) * 64;
#pragma unroll
  for (int g = 0; g < 8; ++g) {
    uint4 v;
    v.x = pk2(y[g*8+0], y[g*8+1]); v.y = pk2(y[g*8+2], y[g*8+3]);
    v.z = pk2(y[g*8+4], y[g*8+5]); v.w = pk2(y[g*8+6], y[g*8+7]);
    *reinterpret_cast<uint4*>(dst + g * 8) = v;
  }
}

// ---------------- G1: QKVp[n][192] = Wqkv(192x64) * Y1
__global__ __launch_bounds__(256, 2) void g_qkvp(
    const u16* __restrict__ Y1, const float* __restrict__ wq,
    u16* __restrict__ qkvp)
{
  const int l = threadIdx.x & 63, fr = l & 15, fq = l >> 4;
  const int wv = blockIdx.x * 4 + (threadIdx.x >> 6);
  const int nw = gridDim.x * 4;
  short8 A[12][2];
#pragma unroll
  for (int t = 0; t < 12; ++t)
#pragma unroll
    for (int kh = 0; kh < 2; ++kh)
      A[t][kh] = afrag(wq, 64, t * 16 + fr, kh * 32 + fq * 8, 64);
  for (int tile = wv; tile < 8192; tile += nw) {
    const size_t n0 = (size_t)tile * 16;
    const u16* yb = Y1 + (n0 + fr) * 64 + fq * 8;
    const short8 b0 = *reinterpret_cast<const short8*>(yb);
    const short8 b1 = *reinterpret_cast<const short8*>(yb + 32);
    f32x4 c[12];
#pragma unroll
    for (int t = 0; t < 12; ++t) c[t] = f32x4{0.f, 0.f, 0.f, 0.f};
#pragma unroll
    for (int t = 0; t < 12; ++t) c[t] = mm(A[t][0], b0, c[t]);
#pragma unroll
    for (int t = 0; t < 12; ++t) c[t] = mm(A[t][1], b1, c[t]);
    u16* ob = qkvp + (n0 + fr) * 192 + fq * 4;
#pragma unroll
    for (int t = 0; t < 12; ++t) st4(ob + t * 16, c[t]);
  }
}

// ---------------- LDS-tiled depthwise 3x3 SAME on pixel-major [n][CIN] bf16.
// Tile: 32x16 outputs, halo 34x18. One 8-channel slice per block (2 planes
// if GATE: x1 slice at col sl*8, x2 slice at col 176+sl*8; gelu(x1)*x2 out).
template<int CIN, int COUT, int NSL, int WOFS, bool GATE, int WLIM>
__global__ __launch_bounds__(256, 4) void k_dwt(
    const u16* __restrict__ in, u16* __restrict__ out,
    const float* __restrict__ wdw)
{
  constexpr int NPL = GATE ? 2 : 1;
  __shared__ __align__(16) u16 sd[NPL][612 * 8];
  __shared__ float sw[NPL][72];

  const int bid = blockIdx.x;
  const int sl = bid % NSL;
  const int rest = bid / NSL;
  const int tile = rest & 127;
  const int b = rest >> 7;
  const int tx0 = (tile & 7) * 32, ty0 = (tile >> 3) * 16;
  const int t = threadIdx.x;

  // stage weights: sw[pl][tap*8+ch]
  for (int i = t; i < NPL * 72; i += 256) {
    const int pl = i / 72, k = i % 72;
    const int tap = k >> 3, ch = k & 7;
    const int wrow = WOFS + pl * 170 + sl * 8 + ch;
    sw[pl][tap * 8 + ch] = (wrow < WLIM) ? wdw[(size_t)wrow * 9 + tap] : 0.f;
  }
  // stage data tile with halo
  const u16* pin = in + (size_t)b * NPB * CIN;
  for (int u = t; u < 612; u += 256) {
    const int py = u / 34, px = u % 34;
    const int yy = ty0 + py - 1, xx = tx0 + px - 1;
    const bool ok = ((unsigned)yy < 256u) && ((unsigned)xx < 256u);
#pragma unroll
    for (int pl = 0; pl < NPL; ++pl) {
      short8 v;
      if (ok) {
        v = *reinterpret_cast<const short8*>(
            pin + ((size_t)(yy * 256 + xx)) * CIN + pl * 176 + sl * 8);
      } else {
#pragma unroll
        for (int i = 0; i < 8; ++i) v[i] = 0;
      }
      *reinterpret_cast<short8*>(&sd[pl][u * 8]) = v;
    }
  }
  __syncthreads();

  // compute: thread -> out cols tx0+ox, rows ty0+oy, ty0+oy+1
  const int ox = t & 31;
  const int oy = (t >> 5) * 2;
  float acc[NPL][2][8];
#pragma unroll
  for (int pl = 0; pl < NPL; ++pl)
#pragma unroll
    for (int p = 0; p < 2; ++p)
#pragma unroll
      for (int i = 0; i < 8; ++i) acc[pl][p][i] = 0.f;

#pragma unroll
  for (int pl = 0; pl < NPL; ++pl) {
#pragma unroll
    for (int r = 0; r < 4; ++r) {
      short8 d[3];
#pragma unroll
      for (int c = 0; c < 3; ++c)
        d[c] = *reinterpret_cast<const short8*>(&sd[pl][((oy + r) * 34 + ox + c) * 8]);
#pragma unroll
      for (int p = 0; p < 2; ++p) {
        const int ky = r - p;
        if (ky < 0 || ky > 2) continue;
#pragma unroll
        for (int kx = 0; kx < 3; ++kx) {
          const float* w = &sw[pl][(ky * 3 + kx) * 8];
#pragma unroll
          for (int i = 0; i < 8; ++i)
            acc[pl][p][i] = fmaf(w[i], bf2f((u16)d[kx][i]), acc[pl][p][i]);
        }
      }
    }
  }

  u16* pout = out + (size_t)b * NPB * COUT;
#pragma unroll
  for (int p = 0; p < 2; ++p) {
    float v[8];
#pragma unroll
    for (int i = 0; i < 8; ++i) {
      if (GATE) {
        const float a = acc[0][p][i];
        v[i] = 0.5f * a * (1.f + erff(a * 0.70710678118f)) * acc[1][p][i];
      } else {
        v[i] = acc[0][p][i];
      }
    }
    uint4 o;
    o.x = pk2(v[0], v[1]); o.y = pk2(v[2], v[3]);
    o.z = pk2(v[4], v[5]); o.w = pk2(v[6], v[7]);
    const int py = ty0 + oy + p, px = tx0 + ox;
    *reinterpret_cast<uint4*>(pout + ((size_t)(py * 256 + px)) * COUT + sl * 8) = o;
  }
}

// ---------------- gram/norm partials via MFMA (Q^T K, Q^T Q, K^T K diag)
__global__ __launch_bounds__(256, 2) void k_gram_p(
    const u16* __restrict__ qkv, float* __restrict__ part)
{
  __shared__ __align__(16) u16 lds[32][520];
  const int chunk = blockIdx.x, h = blockIdx.y, b = blockIdx.z;
  const int t = threadIdx.x;
#pragma unroll
  for (int i = 0; i < 2; ++i) {
    const int p = t + i * 256;
    const u16* src = qkv + ((size_t)(b * NPB) + chunk * 512 + p) * 192 + h * 16;
    const short8 q0 = *reinterpret_cast<const short8*>(src);
    const short8 q1 = *reinterpret_cast<const short8*>(src + 8);
    const short8 k0 = *reinterpret_cast<const short8*>(src + 64);
    const short8 k1 = *reinterpret_cast<const short8*>(src + 72);
#pragma unroll
    for (int j = 0; j < 8; ++j) {
      lds[j][p] = (u16)q0[j];  lds[8 + j][p] = (u16)q1[j];
      lds[16 + j][p] = (u16)k0[j]; lds[24 + j][p] = (u16)k1[j];
    }
  }
  __syncthreads();
  const int w = t >> 6, l = t & 63, fr = l & 15, fq = l >> 4;
  if (w >= 3) return;
  float* pp = part + ((size_t)((b * 4 + h) * 128) + chunk) * 288;
  const int rowA = (w == 2) ? 16 + fr : fr;
  const int rowB = (w == 0) ? 16 + fr : rowA;
  f32x4 acc = {0.f, 0.f, 0.f, 0.f};
#pragma unroll
  for (int kt = 0; kt < 16; ++kt) {
    const short8 a  = *reinterpret_cast<const short8*>(&lds[rowA][kt * 32 + fq * 8]);
    const short8 bb = *reinterpret_cast<const short8*>(&lds[rowB][kt * 32 + fq * 8]);
    acc = mm(a, bb, acc);
  }
  if (w == 0) {
#pragma unroll
    for (int r = 0; r < 4; ++r) pp[(fq * 4 + r) * 16 + fr] = acc[r];
  } else if ((fr >> 2) == fq) {
    pp[(w == 1 ? 256 : 272) + fr] = acc[fr & 3];
  }
}

// ---------------- reduce partials over 128 chunks
__global__ __launch_bounds__(320) void k_gram_red(
    const float* __restrict__ part, float* __restrict__ G,
    float* __restrict__ Sq, float* __restrict__ Sk)
{
  const int bh = blockIdx.x;
  const int t = threadIdx.x;
  if (t >= 288) return;
  const float* p = part + (size_t)bh * 128 * 288 + t;
  float s = 0.f;
  for (int ch = 0; ch < 128; ++ch) s += p[(size_t)ch * 288];
  const int b = bh >> 2, h = bh & 3;
  if (t < 256) G[bh * 256 + t] = s;
  else if (t < 272) Sq[b * 64 + h * 16 + (t - 256)] = s;
  else Sk[b * 64 + h * 16 + (t - 272)] = s;
}

// ---------------- softmax + fold conv matrices (tiny, 1 block)
__global__ __launch_bounds__(256) void k_attn(
    const float* __restrict__ G, const float* __restrict__ Sq,
    const float* __restrict__ Sk, const float* __restrict__ temp,
    const float* __restrict__ wpo, const float* __restrict__ wkv,
    const float* __restrict__ wpof, float* __restrict__ P,
    float* __restrict__ M2)
{
  __shared__ float attn[BATCH][4][16][16];
  __shared__ float M1[BATCH][64][64];
  __shared__ float rq[128], rk[128];
  const int t = threadIdx.x;
  if (t < 128) {
    rq[t] = 1.f / fmaxf(sqrtf(Sq[t]), 1e-12f);
    rk[t] = 1.f / fmaxf(sqrtf(Sk[t]), 1e-12f);
  }
  __syncthreads();
  if (t < 128) {
    const int b = t >> 6, h = (t >> 4) & 3, d = t & 15;
    const float tm = temp[h];
    const float* g = G + ((b * 4 + h) * 16 + d) * 16;
    const float rqd = rq[b * 64 + h * 16 + d];
    float L[16], mx = -1e30f;
#pragma unroll
    for (int e = 0; e < 16; ++e) {
      L[e] = g[e] * rqd * rk[b * 64 + h * 16 + e] * tm;
      mx = fmaxf(mx, L[e]);
    }
    float s = 0.f;
#pragma unroll
    for (int e = 0; e < 16; ++e) { L[e] = expf(L[e] - mx); s += L[e]; }
    const float inv = 1.f / s;
#pragma unroll
    for (int e = 0; e < 16; ++e) attn[b][h][d][e] = L[e] * inv;
  }
  __syncthreads();
  for (int s0 = 0; s0 < 32; ++s0) {
    const int idx = t * 32 + s0;
    const int b = idx >> 12, o = (idx >> 6) & 63, c = idx & 63;
    const int h = c >> 4, e = c & 15;
    float a = 0.f;
#pragma unroll
    for (int d = 0; d < 16; ++d) a = fmaf(wpo[o * 64 + h * 16 + d], attn[b][h][d][e], a);
    M1[b][o][c] = a;
  }
  __syncthreads();
  for (int s0 = 0; s0 < 32; ++s0) {
    const int idx = t * 32 + s0;
    const int b = idx >> 12, o = (idx >> 6) & 63, c = idx & 63;
    const int h = c >> 4, e = c & 15;
    float a = 0.f;
    for (int j = 0; j < 64; ++j) a = fmaf(wkv[(64 + o) * 64 + j], M1[b][j][c], a);
    P[(b * 64 + o) * 64 + c] = a;
    float a2 = 0.f;
#pragma unroll
    for (int d = 0; d < 16; ++d) a2 = fmaf(wpof[o * 64 + h * 16 + d], attn[b][h][d][e], a2);
    M2[(b * 64 + o) * 64 + c] = a2;
  }
}

// ---------------- G2: VFP[n][64] = P_b * v   (v = qkv cols 128..191)
__global__ __launch_bounds__(256, 2) void g_pv(
    const u16* __restrict__ qkv, const float* __restrict__ P,
    u16* __restrict__ vfp)
{
  const int l = threadIdx.x & 63, fr = l & 15, fq = l >> 4;
  const int wv = blockIdx.x * 4 + (threadIdx.x >> 6);
  const int nw = gridDim.x * 4;
  const int b = blockIdx.z;
  const float* Pb = P + b * 4096;
  short8 A[4][2];
#pragma unroll
  for (int t = 0; t < 4; ++t)
#pragma unroll
    for (int kh = 0; kh < 2; ++kh)
      A[t][kh] = afrag(Pb, 64, t * 16 + fr, kh * 32 + fq * 8, 64);
  for (int tile = wv; tile < 4096; tile += nw) {
    const size_t n0 = (size_t)b * NPB + (size_t)tile * 16;
    const u16* yb = qkv + (n0 + fr) * 192 + 128 + fq * 8;
    const short8 b0 = *reinterpret_cast<const short8*>(yb);
    const short8 b1 = *reinterpret_cast<const short8*>(yb + 32);
    f32x4 c[4];
#pragma unroll
    for (int t = 0; t < 4; ++t) c[t] = f32x4{0.f, 0.f, 0.f, 0.f};
#pragma unroll
    for (int t = 0; t < 4; ++t) c[t] = mm(A[t][0], b0, c[t]);
#pragma unroll
    for (int t = 0; t < 4; ++t) c[t] = mm(A[t][1], b1, c[t]);
    u16* ob = vfp + (n0 + fr) * 64 + fq * 4;
#pragma unroll
    for (int t = 0; t < 4; ++t) st4(ob + t * 16, c[t]);
  }
}

// ---------------- G3 fused: X2 = x + M2_b*vf (bf16 out) ; Y2 = LN2(X2)
__global__ __launch_bounds__(256, 2) void g_x2ln(
    const u16* __restrict__ vf, const float* __restrict__ M2,
    const float* __restrict__ x, const float* __restrict__ n2w,
    const float* __restrict__ n2b, u16* __restrict__ X2,
    u16* __restrict__ Y2)
{
  const int l = threadIdx.x & 63, fr = l & 15, fq = l >> 4;
  const int wv = blockIdx.x * 4 + (threadIdx.x >> 6);
  const int nw = gridDim.x * 4;
  const int b = blockIdx.z;
  const float* Mb = M2 + b * 4096;
  short8 A[4][2];
#pragma unroll
  for (int t = 0; t < 4; ++t)
#pragma unroll
    for (int kh = 0; kh < 2; ++kh)
      A[t][kh] = afrag(Mb, 64, t * 16 + fr, kh * 32 + fq * 8, 64);
  for (int tile = wv; tile < 4096; tile += nw) {
    const int pix0 = tile * 16;
    const size_t n0 = (size_t)b * NPB + pix0;
    const u16* yb = vf + (n0 + fr) * 64 + fq * 8;
    const short8 b0 = *reinterpret_cast<const short8*>(yb);
    const short8 b1 = *reinterpret_cast<const short8*>(yb + 32);
    f32x4 c[4];
#pragma unroll
    for (int t = 0; t < 4; ++t) c[t] = f32x4{0.f, 0.f, 0.f, 0.f};
#pragma unroll
    for (int t = 0; t < 4; ++t) c[t] = mm(A[t][0], b0, c[t]);
#pragma unroll
    for (int t = 0; t < 4; ++t) c[t] = mm(A[t][1], b1, c[t]);
    const int pix = pix0 + fr;
#pragma unroll
    for (int t = 0; t < 4; ++t)
#pragma unroll
      for (int r = 0; r < 4; ++r)
        c[t][r] += x[((size_t)(b * 64 + t * 16 + fq * 4 + r)) * NPB + pix];
    u16* xb = X2 + (n0 + fr) * 64 + fq * 4;
#pragma unroll
    for (int t = 0; t < 4; ++t) st4(xb + t * 16, c[t]);
    float s = 0.f;
#pragma unroll
    for (int t = 0; t < 4; ++t)
#pragma unroll
      for (int r = 0; r < 4; ++r) s += c[t][r];
    s += __shfl_xor(s, 16); s += __shfl_xor(s, 32);
    const float mu = s * (1.f / 64.f);
    float ss = 0.f;
#pragma unroll
    for (int t = 0; t < 4; ++t)
#pragma unroll
      for (int r = 0; r < 4; ++r) { float d = c[t][r] - mu; ss = fmaf(d, d, ss); }
    ss += __shfl_xor(ss, 16); ss += __shfl_xor(ss, 32);
    const float rstd = rsqrtf(ss * (1.f / 64.f) + 1e-5f);
#pragma unroll
    for (int t = 0; t < 4; ++t)
#pragma unroll
      for (int r = 0; r < 4; ++r) {
        const int oc = t * 16 + fq * 4 + r;
        c[t][r] = (c[t][r] - mu) * rstd * n2w[oc] + n2b[oc];
      }
    u16* ob = Y2 + (n0 + fr) * 64 + fq * 4;
#pragma unroll
    for (int t = 0; t < 4; ++t) st4(ob + t * 16, c[t]);
  }
}

// ---------------- G4: Hpre[n][352] = Win(340x64 padded) * Y2
__global__ __launch_bounds__(256, 2) void g_win(
    const u16* __restrict__ Y2, const float* __restrict__ win,
    u16* __restrict__ hpre)
{
  const int l = threadIdx.x & 63, fr = l & 15, fq = l >> 4;
  const int wv = blockIdx.x * 4 + (threadIdx.x >> 6);
  const int nw = gridDim.x * 4;
  const int half = wv & 1;
  short8 A[11][2];
#pragma unroll
  for (int t = 0; t < 11; ++t)
#pragma unroll
    for (int kh = 0; kh < 2; ++kh) {
      const int col = half * 176 + t * 16 + fr;
      const int row = col < 170 ? col : (col < 176 ? -1 : (col < 346 ? col - 6 : -1));
      A[t][kh] = afrag(win, 64, row, kh * 32 + fq * 8, 64);
    }
  for (int tile = wv >> 1; tile < 8192; tile += (nw >> 1)) {
    const size_t n0 = (size_t)tile * 16;
    const u16* yb = Y2 + (n0 + fr) * 64 + fq * 8;
    const short8 b0 = *reinterpret_cast<const short8*>(yb);
    const short8 b1 = *reinterpret_cast<const short8*>(yb + 32);
    f32x4 c[11];
#pragma unroll
    for (int t = 0; t < 11; ++t) c[t] = f32x4{0.f, 0.f, 0.f, 0.f};
#pragma unroll
    for (int t = 0; t < 11; ++t) c[t] = mm(A[t][0], b0, c[t]);
#pragma unroll
    for (int t = 0; t < 11; ++t) c[t] = mm(A[t][1], b1, c[t]);
    u16* ob = hpre + (n0 + fr) * 352 + half * 176 + fq * 4;
#pragma unroll
    for (int t = 0; t < 11; ++t) st4(ob + t * 16, c[t]);
  }
}

// ---------------- G5: out = X2 + Wout(64x170) * Hg   (f32 channel-major)
__global__ __launch_bounds__(256, 2) void g_out(
    const u16* __restrict__ hg, const float* __restrict__ wout,
    const u16* __restrict__ X2, float* __restrict__ out)
{
  const int l = threadIdx.x & 63, fr = l & 15, fq = l >> 4;
  const int wv = blockIdx.x * 4 + (threadIdx.x >> 6);
  const int nw = gridDim.x * 4;
  short8 A[4][6];
#pragma unroll
  for (int t = 0; t < 4; ++t)
#pragma unroll
    for (int kh = 0; kh < 6; ++kh)
      A[t][kh] = afrag(wout, 170, t * 16 + fr, kh * 32 + fq * 8, 170);
  for (int tile = wv; tile < 8192; tile += nw) {
    const size_t n0 = (size_t)tile * 16;
    f32x4 c[4];
#pragma unroll
    for (int t = 0; t < 4; ++t) c[t] = f32x4{0.f, 0.f, 0.f, 0.f};
#pragma unroll
    for (int kh = 0; kh < 6; ++kh) {
      const short8 bb = *reinterpret_cast<const short8*>(
          hg + (n0 + fr) * 176 + kh * 32 + fq * 8);
#pragma unroll
      for (int t = 0; t < 4; ++t) c[t] = mm(A[t][kh], bb, c[t]);
    }
    const int b = (int)(n0 >> 16);
    const int pix = ((int)n0 & 65535) + fr;
#pragma unroll
    for (int t = 0; t < 4; ++t) {
      const uint2 xv = *reinterpret_cast<const uint2*>(
          X2 + (n0 + fr) * 64 + t * 16 + fq * 4);
      const u16 h0 = (u16)(xv.x & 0xffff), h1 = (u16)(xv.x >> 16);
      const u16 h2 = (u16)(xv.y & 0xffff), h3 = (u16)(xv.y >> 16);
      const int ocb = b * 64 + t * 16 + fq * 4;
      out[((size_t)(ocb + 0)) * NPB + pix] = c[t][0] + bf2f(h0);
      out[((size_t)(ocb + 1)) * NPB + pix] = c[t][1] + bf2f(h1);
      out[((size_t)(ocb + 2)) * NPB + pix] = c[t][2] + bf2f(h2);
      out[((size_t)(ocb + 3)) * NPB + pix] = c[t][3] + bf2f(h3);
    }
  }
}

extern "C" void kernel_launch(void* const* d_in, const int* in_sizes, int n_in,
                              void* d_out, int out_size, void* d_ws, size_t ws_size,
                              hipStream_t stream)
{
  const float* x     = (const float*)d_in[0];
  const float* n1w   = (const float*)d_in[1];
  const float* n1b   = (const float*)d_in[2];
  const float* temp  = (const float*)d_in[3];
  const float* wqkv  = (const float*)d_in[4];
  const float* wqkvd = (const float*)d_in[5];
  const float* wpo   = (const float*)d_in[6];
  const float* wkv   = (const float*)d_in[7];
  const float* wkvd  = (const float*)d_in[8];
  const float* wpof  = (const float*)d_in[9];
  const float* n2w   = (const float*)d_in[10];
  const float* n2b   = (const float*)d_in[11];
  const float* win   = (const float*)d_in[12];
  const float* wdw   = (const float*)d_in[13];
  const float* wout  = (const float*)d_in[14];
  float* out = (float*)d_out;

  char* ws = (char*)d_ws;
  const size_t offA  = 0;                       // 16.78 MB: Y1 / VFP / Y2
  const size_t offB  = 16777216;                // 50.33 MB: QKVp / VF / Hpre(start)
  const size_t offC  = offB + 50331648;         // 50.33 MB: QKV / Hpre(cont)
  const size_t offHg = offC + 50331648;         // 46.14 MB + slack
  const size_t offX2 = offHg + 46137344 + 256;  // 16.78 MB
  const size_t offSm = offX2 + 16777216;

  u16* Y1   = (u16*)(ws + offA);
  u16* VFP  = (u16*)(ws + offA);
  u16* Y2   = (u16*)(ws + offA);
  u16* QKVp = (u16*)(ws + offB);
  u16* VF   = (u16*)(ws + offB);
  u16* Hpre = (u16*)(ws + offB);   // spans B+C (92.3 MB <= 100.7 MB)
  u16* QKV  = (u16*)(ws + offC);
  u16* Hg   = (u16*)(ws + offHg);
  u16* X2   = (u16*)(ws + offX2);
  float* part = (float*)(ws + offSm);                     // 1,179,648 B
  float* G    = (float*)(ws + offSm + 1179648);           // 8 KB
  float* Sq   = (float*)(ws + offSm + 1179648 + 8192);    // 512 B
  float* Sk   = (float*)(ws + offSm + 1179648 + 8704);    // 512 B
  float* P    = (float*)(ws + offSm + 1179648 + 9216);    // 32 KB
  float* M2   = (float*)(ws + offSm + 1179648 + 41984);   // 32 KB

  k_ln1<<<dim3(NPB / 256, BATCH), 256, 0, stream>>>(x, n1w, n1b, Y1);
  g_qkvp<<<dim3(512), 256, 0, stream>>>(Y1, wqkv, QKVp);
  // dw 192ch: 24 slices x 128 tiles x 2 batches
  k_dwt<192, 192, 24, 0, false, (1 << 30)>
      <<<dim3(24 * 128 * BATCH), 256, 0, stream>>>(QKVp, QKV, wqkvd);
  k_gram_p<<<dim3(128, 4, BATCH), 256, 0, stream>>>(QKV, part);
  k_gram_red<<<dim3(BATCH * 4), 320, 0, stream>>>(part, G, Sq, Sk);
  k_attn<<<dim3(1), 256, 0, stream>>>(G, Sq, Sk, temp, wpo, wkv, wpof, P, M2);
  g_pv<<<dim3(256, 1, BATCH), 256, 0, stream>>>(QKV, P, VFP);
  // dw 64ch (kv branch, weight rows 64..127): 8 slices
  k_dwt<64, 64, 8, 64, false, (1 << 30)>
      <<<dim3(8 * 128 * BATCH), 256, 0, stream>>>(VFP, VF, wkvd);
  g_x2ln<<<dim3(256, 1, BATCH), 256, 0, stream>>>(VF, M2, x, n2w, n2b, X2, Y2);
  g_win<<<dim3(512), 256, 0, stream>>>(Y2, win, Hpre);
  // dw 352ch gated -> Hg[176]: 22 slice-pairs
  k_dwt<352, 176, 22, 0, true, 340>
      <<<dim3(22 * 128 * BATCH), 256, 0, stream>>>(Hpre, Hg, wdw);
  g_out<<<dim3(512), 256, 0, stream>>>(Hg, wout, X2, out);
}

// Round 4
// 1246.156 us; speedup vs baseline: 1.1074x; 1.1074x over previous
//
#include <hip/hip_runtime.h>
#include <hip/hip_bf16.h>
#include <math.h>

#define NPB 65536   // pixels per batch (256*256)
#define BATCH 2
#define NTOT (BATCH * NPB)   // 131072

typedef unsigned short u16;
typedef __attribute__((ext_vector_type(8))) short short8;
typedef __attribute__((ext_vector_type(4))) float f32x4;

// ---- channel-blocked pixel-major layout for all bf16 intermediates:
//   elem(cb, n, c) at  T[((size_t)cb * NTOT + n) * 16 + c],  c in [0,16)
// so each 16-channel block is a dense contiguous [n][16] stream (32 B/pixel).

__device__ __forceinline__ float bf2f(u16 u) {
  union { unsigned u; float f; } v; v.u = ((unsigned)u) << 16; return v.f;
}
__device__ __forceinline__ u16 f2bf(float f) {
  union { float f; unsigned u; } v; v.f = f;
  unsigned r = v.u + 0x7FFFu + ((v.u >> 16) & 1u);
  return (u16)(r >> 16);
}
__device__ __forceinline__ unsigned pk2(float a, float b) {
  return (unsigned)f2bf(a) | ((unsigned)f2bf(b) << 16);
}
__device__ __forceinline__ f32x4 mm(short8 a, short8 b, f32x4 c) {
  return __builtin_amdgcn_mfma_f32_16x16x32_bf16(a, b, c, 0, 0, 0);
}
__device__ __forceinline__ short8 afrag(const float* W, int ld, int row, int k0, int kval) {
  short8 r;
#pragma unroll
  for (int j = 0; j < 8; ++j) {
    float v = 0.f;
    if (row >= 0 && (k0 + j) < kval) v = W[(size_t)row * ld + k0 + j];
    r[j] = (short)f2bf(v);
  }
  return r;
}
__device__ __forceinline__ void st4(u16* p, f32x4 c) {
  uint2 v; v.x = pk2(c[0], c[1]); v.y = pk2(c[2], c[3]);
  *reinterpret_cast<uint2*>(p) = v;
}

// ---------------- K1: LN1, channel-major f32 -> blocked bf16 (4 blocks)
__global__ __launch_bounds__(256, 4) void k_ln1(
    const float* __restrict__ x, const float* __restrict__ n1w,
    const float* __restrict__ n1b, u16* __restrict__ Y1)
{
  const int n = blockIdx.x * 256 + threadIdx.x;
  const int b = blockIdx.y;
  const size_t pix = (size_t)b * NPB + n;
  const float* xb = x + ((size_t)b * 64) * NPB + n;
  float y[64];
  float mu = 0.f;
#pragma unroll
  for (int c = 0; c < 64; ++c) { y[c] = xb[(size_t)c * NPB]; mu += y[c]; }
  mu *= (1.f / 64.f);
  float var = 0.f;
#pragma unroll
  for (int c = 0; c < 64; ++c) { float d = y[c] - mu; var = fmaf(d, d, var); }
  const float rstd = rsqrtf(var * (1.f / 64.f) + 1e-5f);
#pragma unroll
  for (int c = 0; c < 64; ++c) y[c] = (y[c] - mu) * rstd * n1w[c] + n1b[c];
#pragma unroll
  for (int cb = 0; cb < 4; ++cb) {
    u16* dst = Y1 + ((size_t)cb * NTOT + pix) * 16;
    uint4 v0, v1;
    v0.x = pk2(y[cb*16+0],  y[cb*16+1]);  v0.y = pk2(y[cb*16+2],  y[cb*16+3]);
    v0.z = pk2(y[cb*16+4],  y[cb*16+5]);  v0.w = pk2(y[cb*16+6],  y[cb*16+7]);
    v1.x = pk2(y[cb*16+8],  y[cb*16+9]);  v1.y = pk2(y[cb*16+10], y[cb*16+11]);
    v1.z = pk2(y[cb*16+12], y[cb*16+13]); v1.w = pk2(y[cb*16+14], y[cb*16+15]);
    *reinterpret_cast<uint4*>(dst) = v0;
    *reinterpret_cast<uint4*>(dst + 8) = v1;
  }
}

// ---------------- G1: QKVp (12 blocks) = Wqkv(192x64) * Y1
__global__ __launch_bounds__(256, 2) void g_qkvp(
    const u16* __restrict__ Y1, const float* __restrict__ wq,
    u16* __restrict__ qkvp)
{
  const int l = threadIdx.x & 63, fr = l & 15, fq = l >> 4;
  const int wv = blockIdx.x * 4 + (threadIdx.x >> 6);
  const int nw = gridDim.x * 4;
  short8 A[12][2];
#pragma unroll
  for (int t = 0; t < 12; ++t)
#pragma unroll
    for (int kh = 0; kh < 2; ++kh)
      A[t][kh] = afrag(wq, 64, t * 16 + fr, kh * 32 + fq * 8, 64);
  const size_t hof = (size_t)(fq & 1) * 8;
  for (int tile = wv; tile < 8192; tile += nw) {
    const size_t n = (size_t)tile * 16 + fr;
    const short8 b0 = *reinterpret_cast<const short8*>(
        Y1 + (((size_t)(fq >> 1)) * NTOT + n) * 16 + hof);
    const short8 b1 = *reinterpret_cast<const short8*>(
        Y1 + (((size_t)(2 + (fq >> 1))) * NTOT + n) * 16 + hof);
    f32x4 c[12];
#pragma unroll
    for (int t = 0; t < 12; ++t) c[t] = f32x4{0.f, 0.f, 0.f, 0.f};
#pragma unroll
    for (int t = 0; t < 12; ++t) c[t] = mm(A[t][0], b0, c[t]);
#pragma unroll
    for (int t = 0; t < 12; ++t) c[t] = mm(A[t][1], b1, c[t]);
#pragma unroll
    for (int t = 0; t < 12; ++t)
      st4(qkvp + ((size_t)t * NTOT + n) * 16 + fq * 4, c[t]);
  }
}

// ---------------- LDS-tiled depthwise 3x3 SAME on blocked layout.
// Block: one 16-ch block x 32x16 spatial tile (halo 34x18), contiguous loads.
// GATE: plane0 = cb, plane1 = cb+11 (x2 gate); out = gelu(x1)*x2 at block cb.
template<int WOFS, bool GATE, int WLIM>
__global__ __launch_bounds__(256, 2) void k_dwt(
    const u16* __restrict__ in, u16* __restrict__ out,
    const float* __restrict__ wdw)
{
  constexpr int NPL = GATE ? 2 : 1;
  __shared__ __align__(16) u16 sd[NPL][612 * 16];
  __shared__ float sw[NPL][144];
  const int tile = blockIdx.x;
  const int cb = blockIdx.y;
  const int b = blockIdx.z;
  const int tx0 = (tile & 7) * 32, ty0 = (tile >> 3) * 16;
  const int t = threadIdx.x;
  const size_t bofs = (size_t)b * NPB;

  for (int i = t; i < NPL * 144; i += 256) {
    const int pl = i / 144, k = i % 144;
    const int tap = k >> 4, ch = k & 15;
    const int c = cb * 16 + ch;
    int wrow; bool valid;
    if (GATE) { valid = c < 170; wrow = pl * 170 + c; }
    else { wrow = WOFS + c; valid = wrow < WLIM; }
    sw[pl][tap * 16 + ch] = valid ? wdw[(size_t)wrow * 9 + tap] : 0.f;
  }
  for (int i = t; i < 1224; i += 256) {
    const int p = i >> 1, hf = i & 1;
    const int py = p / 34, px = p % 34;
    const int yy = ty0 + py - 1, xx = tx0 + px - 1;
    const bool ok = ((unsigned)yy < 256u) && ((unsigned)xx < 256u);
#pragma unroll
    for (int pl = 0; pl < NPL; ++pl) {
      short8 v;
#pragma unroll
      for (int j = 0; j < 8; ++j) v[j] = 0;
      if (ok)
        v = *reinterpret_cast<const short8*>(
            in + (((size_t)(cb + pl * 11)) * NTOT + bofs + yy * 256 + xx) * 16 + hf * 8);
      *reinterpret_cast<short8*>(&sd[pl][p * 16 + hf * 8]) = v;
    }
  }
  __syncthreads();

  const int ox = t & 31;
  const int oy = (t >> 5) * 2;
  float acc[NPL][2][16];
#pragma unroll
  for (int pl = 0; pl < NPL; ++pl)
#pragma unroll
    for (int p = 0; p < 2; ++p)
#pragma unroll
      for (int i = 0; i < 16; ++i) acc[pl][p][i] = 0.f;

#pragma unroll
  for (int pl = 0; pl < NPL; ++pl) {
#pragma unroll
    for (int r = 0; r < 4; ++r) {
      short8 d0[3], d1[3];
#pragma unroll
      for (int c = 0; c < 3; ++c) {
        const int base = ((oy + r) * 34 + ox + c) * 16;
        d0[c] = *reinterpret_cast<const short8*>(&sd[pl][base]);
        d1[c] = *reinterpret_cast<const short8*>(&sd[pl][base + 8]);
      }
#pragma unroll
      for (int p = 0; p < 2; ++p) {
        const int ky = r - p;
        if (ky < 0 || ky > 2) continue;
#pragma unroll
        for (int kx = 0; kx < 3; ++kx) {
          const float* w = &sw[pl][(ky * 3 + kx) * 16];
#pragma unroll
          for (int i = 0; i < 8; ++i) {
            acc[pl][p][i]     = fmaf(w[i],     bf2f((u16)d0[kx][i]), acc[pl][p][i]);
            acc[pl][p][8 + i] = fmaf(w[8 + i], bf2f((u16)d1[kx][i]), acc[pl][p][8 + i]);
          }
        }
      }
    }
  }

#pragma unroll
  for (int p = 0; p < 2; ++p) {
    float v[16];
#pragma unroll
    for (int i = 0; i < 16; ++i) {
      if (GATE) {
        const float a = acc[0][p][i];
        v[i] = 0.5f * a * (1.f + erff(a * 0.70710678118f)) * acc[1][p][i];
      } else {
        v[i] = acc[0][p][i];
      }
    }
    u16* po = out + (((size_t)cb) * NTOT + bofs +
                     (size_t)((ty0 + oy + p) * 256 + tx0 + ox)) * 16;
    uint4 o0, o1;
    o0.x = pk2(v[0], v[1]);   o0.y = pk2(v[2], v[3]);
    o0.z = pk2(v[4], v[5]);   o0.w = pk2(v[6], v[7]);
    o1.x = pk2(v[8], v[9]);   o1.y = pk2(v[10], v[11]);
    o1.z = pk2(v[12], v[13]); o1.w = pk2(v[14], v[15]);
    *reinterpret_cast<uint4*>(po) = o0;
    *reinterpret_cast<uint4*>(po + 8) = o1;
  }
}

// ---------------- gram/norm partials via MFMA (blocked: q=block h, k=block 4+h)
__global__ __launch_bounds__(256, 2) void k_gram_p(
    const u16* __restrict__ qkv, float* __restrict__ part)
{
  __shared__ __align__(16) u16 lds[32][520];
  const int chunk = blockIdx.x, h = blockIdx.y, b = blockIdx.z;
  const int t = threadIdx.x;
#pragma unroll
  for (int i = 0; i < 2; ++i) {
    const int p = t + i * 256;
    const size_t pix = (size_t)b * NPB + chunk * 512 + p;
    const u16* srcq = qkv + ((size_t)h * NTOT + pix) * 16;
    const u16* srck = qkv + ((size_t)(4 + h) * NTOT + pix) * 16;
    const short8 q0 = *reinterpret_cast<const short8*>(srcq);
    const short8 q1 = *reinterpret_cast<const short8*>(srcq + 8);
    const short8 k0 = *reinterpret_cast<const short8*>(srck);
    const short8 k1 = *reinterpret_cast<const short8*>(srck + 8);
#pragma unroll
    for (int j = 0; j < 8; ++j) {
      lds[j][p] = (u16)q0[j];  lds[8 + j][p] = (u16)q1[j];
      lds[16 + j][p] = (u16)k0[j]; lds[24 + j][p] = (u16)k1[j];
    }
  }
  __syncthreads();
  const int w = t >> 6, l = t & 63, fr = l & 15, fq = l >> 4;
  if (w >= 3) return;
  float* pp = part + ((size_t)((b * 4 + h) * 128) + chunk) * 288;
  const int rowA = (w == 2) ? 16 + fr : fr;
  const int rowB = (w == 0) ? 16 + fr : rowA;
  f32x4 acc = {0.f, 0.f, 0.f, 0.f};
#pragma unroll
  for (int kt = 0; kt < 16; ++kt) {
    const short8 a  = *reinterpret_cast<const short8*>(&lds[rowA][kt * 32 + fq * 8]);
    const short8 bb = *reinterpret_cast<const short8*>(&lds[rowB][kt * 32 + fq * 8]);
    acc = mm(a, bb, acc);
  }
  if (w == 0) {
#pragma unroll
    for (int r = 0; r < 4; ++r) pp[(fq * 4 + r) * 16 + fr] = acc[r];
  } else if ((fr >> 2) == fq) {
    pp[(w == 1 ? 256 : 272) + fr] = acc[fr & 3];
  }
}

// ---------------- reduce partials over 128 chunks
__global__ __launch_bounds__(320) void k_gram_red(
    const float* __restrict__ part, float* __restrict__ G,
    float* __restrict__ Sq, float* __restrict__ Sk)
{
  const int bh = blockIdx.x;
  const int t = threadIdx.x;
  if (t >= 288) return;
  const float* p = part + (size_t)bh * 128 * 288 + t;
  float s = 0.f;
  for (int ch = 0; ch < 128; ++ch) s += p[(size_t)ch * 288];
  const int b = bh >> 2, h = bh & 3;
  if (t < 256) G[bh * 256 + t] = s;
  else if (t < 272) Sq[b * 64 + h * 16 + (t - 256)] = s;
  else Sk[b * 64 + h * 16 + (t - 272)] = s;
}

// ---------------- softmax + fold conv matrices (tiny, 1 block)
__global__ __launch_bounds__(256) void k_attn(
    const float* __restrict__ G, const float* __restrict__ Sq,
    const float* __restrict__ Sk, const float* __restrict__ temp,
    const float* __restrict__ wpo, const float* __restrict__ wkv,
    const float* __restrict__ wpof, float* __restrict__ P,
    float* __restrict__ M2)
{
  __shared__ float attn[BATCH][4][16][16];
  __shared__ float M1[BATCH][64][64];
  __shared__ float rq[128], rk[128];
  const int t = threadIdx.x;
  if (t < 128) {
    rq[t] = 1.f / fmaxf(sqrtf(Sq[t]), 1e-12f);
    rk[t] = 1.f / fmaxf(sqrtf(Sk[t]), 1e-12f);
  }
  __syncthreads();
  if (t < 128) {
    const int b = t >> 6, h = (t >> 4) & 3, d = t & 15;
    const float tm = temp[h];
    const float* g = G + ((b * 4 + h) * 16 + d) * 16;
    const float rqd = rq[b * 64 + h * 16 + d];
    float L[16], mx = -1e30f;
#pragma unroll
    for (int e = 0; e < 16; ++e) {
      L[e] = g[e] * rqd * rk[b * 64 + h * 16 + e] * tm;
      mx = fmaxf(mx, L[e]);
    }
    float s = 0.f;
#pragma unroll
    for (int e = 0; e < 16; ++e) { L[e] = expf(L[e] - mx); s += L[e]; }
    const float inv = 1.f / s;
#pragma unroll
    for (int e = 0; e < 16; ++e) attn[b][h][d][e] = L[e] * inv;
  }
  __syncthreads();
  for (int s0 = 0; s0 < 32; ++s0) {
    const int idx = t * 32 + s0;
    const int b = idx >> 12, o = (idx >> 6) & 63, c = idx & 63;
    const int h = c >> 4, e = c & 15;
    float a = 0.f;
#pragma unroll
    for (int d = 0; d < 16; ++d) a = fmaf(wpo[o * 64 + h * 16 + d], attn[b][h][d][e], a);
    M1[b][o][c] = a;
  }
  __syncthreads();
  for (int s0 = 0; s0 < 32; ++s0) {
    const int idx = t * 32 + s0;
    const int b = idx >> 12, o = (idx >> 6) & 63, c = idx & 63;
    const int h = c >> 4, e = c & 15;
    float a = 0.f;
    for (int j = 0; j < 64; ++j) a = fmaf(wkv[(64 + o) * 64 + j], M1[b][j][c], a);
    P[(b * 64 + o) * 64 + c] = a;
    float a2 = 0.f;
#pragma unroll
    for (int d = 0; d < 16; ++d) a2 = fmaf(wpof[o * 64 + h * 16 + d], attn[b][h][d][e], a2);
    M2[(b * 64 + o) * 64 + c] = a2;
  }
}

// ---------------- G2: VFP (4 blocks) = P_b * v (qkv blocks 8..11)
__global__ __launch_bounds__(256, 2) void g_pv(
    const u16* __restrict__ qkv, const float* __restrict__ P,
    u16* __restrict__ vfp)
{
  const int l = threadIdx.x & 63, fr = l & 15, fq = l >> 4;
  const int wv = blockIdx.x * 4 + (threadIdx.x >> 6);
  const int nw = gridDim.x * 4;
  const int b = blockIdx.z;
  const float* Pb = P + b * 4096;
  short8 A[4][2];
#pragma unroll
  for (int t = 0; t < 4; ++t)
#pragma unroll
    for (int kh = 0; kh < 2; ++kh)
      A[t][kh] = afrag(Pb, 64, t * 16 + fr, kh * 32 + fq * 8, 64);
  const size_t hof = (size_t)(fq & 1) * 8;
  for (int tile = wv; tile < 4096; tile += nw) {
    const size_t n = (size_t)b * NPB + (size_t)tile * 16 + fr;
    const short8 b0 = *reinterpret_cast<const short8*>(
        qkv + ((size_t)(8 + (fq >> 1)) * NTOT + n) * 16 + hof);
    const short8 b1 = *reinterpret_cast<const short8*>(
        qkv + ((size_t)(10 + (fq >> 1)) * NTOT + n) * 16 + hof);
    f32x4 c[4];
#pragma unroll
    for (int t = 0; t < 4; ++t) c[t] = f32x4{0.f, 0.f, 0.f, 0.f};
#pragma unroll
    for (int t = 0; t < 4; ++t) c[t] = mm(A[t][0], b0, c[t]);
#pragma unroll
    for (int t = 0; t < 4; ++t) c[t] = mm(A[t][1], b1, c[t]);
#pragma unroll
    for (int t = 0; t < 4; ++t)
      st4(vfp + ((size_t)t * NTOT + n) * 16 + fq * 4, c[t]);
  }
}

// ---------------- G3 fused: X2 = x + M2_b*vf (bf16); Y2 = LN2(X2)
__global__ __launch_bounds__(256, 2) void g_x2ln(
    const u16* __restrict__ vf, const float* __restrict__ M2,
    const float* __restrict__ x, const float* __restrict__ n2w,
    const float* __restrict__ n2b, u16* __restrict__ X2,
    u16* __restrict__ Y2)
{
  const int l = threadIdx.x & 63, fr = l & 15, fq = l >> 4;
  const int wv = blockIdx.x * 4 + (threadIdx.x >> 6);
  const int nw = gridDim.x * 4;
  const int b = blockIdx.z;
  const float* Mb = M2 + b * 4096;
  short8 A[4][2];
#pragma unroll
  for (int t = 0; t < 4; ++t)
#pragma unroll
    for (int kh = 0; kh < 2; ++kh)
      A[t][kh] = afrag(Mb, 64, t * 16 + fr, kh * 32 + fq * 8, 64);
  const size_t hof = (size_t)(fq & 1) * 8;
  for (int tile = wv; tile < 4096; tile += nw) {
    const int pix0 = tile * 16;
    const size_t n = (size_t)b * NPB + pix0 + fr;
    const short8 b0 = *reinterpret_cast<const short8*>(
        vf + ((size_t)(fq >> 1) * NTOT + n) * 16 + hof);
    const short8 b1 = *reinterpret_cast<const short8*>(
        vf + ((size_t)(2 + (fq >> 1)) * NTOT + n) * 16 + hof);
    f32x4 c[4];
#pragma unroll
    for (int t = 0; t < 4; ++t) c[t] = f32x4{0.f, 0.f, 0.f, 0.f};
#pragma unroll
    for (int t = 0; t < 4; ++t) c[t] = mm(A[t][0], b0, c[t]);
#pragma unroll
    for (int t = 0; t < 4; ++t) c[t] = mm(A[t][1], b1, c[t]);
    const int pix = pix0 + fr;
#pragma unroll
    for (int t = 0; t < 4; ++t)
#pragma unroll
      for (int r = 0; r < 4; ++r)
        c[t][r] += x[((size_t)(b * 64 + t * 16 + fq * 4 + r)) * NPB + pix];
#pragma unroll
    for (int t = 0; t < 4; ++t)
      st4(X2 + ((size_t)t * NTOT + n) * 16 + fq * 4, c[t]);
    float s = 0.f;
#pragma unroll
    for (int t = 0; t < 4; ++t)
#pragma unroll
      for (int r = 0; r < 4; ++r) s += c[t][r];
    s += __shfl_xor(s, 16); s += __shfl_xor(s, 32);
    const float mu = s * (1.f / 64.f);
    float ss = 0.f;
#pragma unroll
    for (int t = 0; t < 4; ++t)
#pragma unroll
      for (int r = 0; r < 4; ++r) { float d = c[t][r] - mu; ss = fmaf(d, d, ss); }
    ss += __shfl_xor(ss, 16); ss += __shfl_xor(ss, 32);
    const float rstd = rsqrtf(ss * (1.f / 64.f) + 1e-5f);
#pragma unroll
    for (int t = 0; t < 4; ++t)
#pragma unroll
      for (int r = 0; r < 4; ++r) {
        const int oc = t * 16 + fq * 4 + r;
        c[t][r] = (c[t][r] - mu) * rstd * n2w[oc] + n2b[oc];
      }
#pragma unroll
    for (int t = 0; t < 4; ++t)
      st4(Y2 + ((size_t)t * NTOT + n) * 16 + fq * 4, c[t]);
  }
}

// ---------------- G4: Hpre (22 blocks) = Win(340x64 padded) * Y2
__global__ __launch_bounds__(256, 2) void g_win(
    const u16* __restrict__ Y2, const float* __restrict__ win,
    u16* __restrict__ hpre)
{
  const int l = threadIdx.x & 63, fr = l & 15, fq = l >> 4;
  const int wv = blockIdx.x * 4 + (threadIdx.x >> 6);
  const int nw = gridDim.x * 4;
  const int half = wv & 1;
  short8 A[11][2];
#pragma unroll
  for (int t = 0; t < 11; ++t)
#pragma unroll
    for (int kh = 0; kh < 2; ++kh) {
      const int col = half * 176 + t * 16 + fr;
      const int row = col < 170 ? col : (col < 176 ? -1 : (col < 346 ? col - 6 : -1));
      A[t][kh] = afrag(win, 64, row, kh * 32 + fq * 8, 64);
    }
  const size_t hof = (size_t)(fq & 1) * 8;
  for (int tile = wv >> 1; tile < 8192; tile += (nw >> 1)) {
    const size_t n = (size_t)tile * 16 + fr;
    const short8 b0 = *reinterpret_cast<const short8*>(
        Y2 + ((size_t)(fq >> 1) * NTOT + n) * 16 + hof);
    const short8 b1 = *reinterpret_cast<const short8*>(
        Y2 + ((size_t)(2 + (fq >> 1)) * NTOT + n) * 16 + hof);
    f32x4 c[11];
#pragma unroll
    for (int t = 0; t < 11; ++t) c[t] = f32x4{0.f, 0.f, 0.f, 0.f};
#pragma unroll
    for (int t = 0; t < 11; ++t) c[t] = mm(A[t][0], b0, c[t]);
#pragma unroll
    for (int t = 0; t < 11; ++t) c[t] = mm(A[t][1], b1, c[t]);
#pragma unroll
    for (int t = 0; t < 11; ++t)
      st4(hpre + ((size_t)(half * 11 + t) * NTOT + n) * 16 + fq * 4, c[t]);
  }
}

// ---------------- G5: out = X2 + Wout(64x170) * Hg (11 blocks)
__global__ __launch_bounds__(256, 2) void g_out(
    const u16* __restrict__ hg, const float* __restrict__ wout,
    const u16* __restrict__ X2, float* __restrict__ out)
{
  const int l = threadIdx.x & 63, fr = l & 15, fq = l >> 4;
  const int wv = blockIdx.x * 4 + (threadIdx.x >> 6);
  const int nw = gridDim.x * 4;
  short8 A[4][6];
#pragma unroll
  for (int t = 0; t < 4; ++t)
#pragma unroll
    for (int kh = 0; kh < 6; ++kh)
      A[t][kh] = afrag(wout, 170, t * 16 + fr, kh * 32 + fq * 8, 170);
  const size_t hof = (size_t)(fq & 1) * 8;
  for (int tile = wv; tile < 8192; tile += nw) {
    const size_t n = (size_t)tile * 16 + fr;
    f32x4 c[4];
#pragma unroll
    for (int t = 0; t < 4; ++t) c[t] = f32x4{0.f, 0.f, 0.f, 0.f};
#pragma unroll
    for (int kh = 0; kh < 6; ++kh) {
      int hb = kh * 2 + (fq >> 1);
      if (hb > 10) hb = 10;  // k>=170 weights are zero; value irrelevant
      const short8 bb = *reinterpret_cast<const short8*>(
          hg + ((size_t)hb * NTOT + n) * 16 + hof);
#pragma unroll
      for (int t = 0; t < 4; ++t) c[t] = mm(A[t][kh], bb, c[t]);
    }
    const int b = (int)(n >> 16);
    const int pix = (int)(n & 65535);
#pragma unroll
    for (int t = 0; t < 4; ++t) {
      const uint2 xv = *reinterpret_cast<const uint2*>(
          X2 + ((size_t)t * NTOT + n) * 16 + fq * 4);
      const u16 h0 = (u16)(xv.x & 0xffff), h1 = (u16)(xv.x >> 16);
      const u16 h2 = (u16)(xv.y & 0xffff), h3 = (u16)(xv.y >> 16);
      const int ocb = b * 64 + t * 16 + fq * 4;
      out[((size_t)(ocb + 0)) * NPB + pix] = c[t][0] + bf2f(h0);
      out[((size_t)(ocb + 1)) * NPB + pix] = c[t][1] + bf2f(h1);
      out[((size_t)(ocb + 2)) * NPB + pix] = c[t][2] + bf2f(h2);
      out[((size_t)(ocb + 3)) * NPB + pix] = c[t][3] + bf2f(h3);
    }
  }
}

extern "C" void kernel_launch(void* const* d_in, const int* in_sizes, int n_in,
                              void* d_out, int out_size, void* d_ws, size_t ws_size,
                              hipStream_t stream)
{
  const float* x     = (const float*)d_in[0];
  const float* n1w   = (const float*)d_in[1];
  const float* n1b   = (const float*)d_in[2];
  const float* temp  = (const float*)d_in[3];
  const float* wqkv  = (const float*)d_in[4];
  const float* wqkvd = (const float*)d_in[5];
  const float* wpo   = (const float*)d_in[6];
  const float* wkv   = (const float*)d_in[7];
  const float* wkvd  = (const float*)d_in[8];
  const float* wpof  = (const float*)d_in[9];
  const float* n2w   = (const float*)d_in[10];
  const float* n2b   = (const float*)d_in[11];
  const float* win   = (const float*)d_in[12];
  const float* wdw   = (const float*)d_in[13];
  const float* wout  = (const float*)d_in[14];
  float* out = (float*)d_out;

  char* ws = (char*)d_ws;
  const size_t offA  = 0;                       // 16.78 MB: Y1 / VFP / Y2
  const size_t offB  = 16777216;                // 50.33 MB: QKVp / VF / Hpre(start)
  const size_t offC  = offB + 50331648;         // 50.33 MB: QKV / Hpre(cont)
  const size_t offHg = offC + 50331648;         // 46.14 MB (11 blocks exactly)
  const size_t offX2 = offHg + 46137344 + 256;  // 16.78 MB
  const size_t offSm = offX2 + 16777216;

  u16* Y1   = (u16*)(ws + offA);
  u16* VFP  = (u16*)(ws + offA);
  u16* Y2   = (u16*)(ws + offA);
  u16* QKVp = (u16*)(ws + offB);
  u16* VF   = (u16*)(ws + offB);
  u16* Hpre = (u16*)(ws + offB);   // 22 blocks span B+C (92.3 MB <= 100.7 MB)
  u16* QKV  = (u16*)(ws + offC);
  u16* Hg   = (u16*)(ws + offHg);
  u16* X2   = (u16*)(ws + offX2);
  float* part = (float*)(ws + offSm);                     // 1,179,648 B
  float* G    = (float*)(ws + offSm + 1179648);           // 8 KB
  float* Sq   = (float*)(ws + offSm + 1179648 + 8192);    // 512 B
  float* Sk   = (float*)(ws + offSm + 1179648 + 8704);    // 512 B
  float* P    = (float*)(ws + offSm + 1179648 + 9216);    // 32 KB
  float* M2   = (float*)(ws + offSm + 1179648 + 41984);   // 32 KB

  k_ln1<<<dim3(NPB / 256, BATCH), 256, 0, stream>>>(x, n1w, n1b, Y1);
  g_qkvp<<<dim3(512), 256, 0, stream>>>(Y1, wqkv, QKVp);
  k_dwt<0, false, (1 << 30)>
      <<<dim3(128, 12, BATCH), 256, 0, stream>>>(QKVp, QKV, wqkvd);
  k_gram_p<<<dim3(128, 4, BATCH), 256, 0, stream>>>(QKV, part);
  k_gram_red<<<dim3(BATCH * 4), 320, 0, stream>>>(part, G, Sq, Sk);
  k_attn<<<dim3(1), 256, 0, stream>>>(G, Sq, Sk, temp, wpo, wkv, wpof, P, M2);
  g_pv<<<dim3(256, 1, BATCH), 256, 0, stream>>>(QKV, P, VFP);
  k_dwt<64, false, (1 << 30)>
      <<<dim3(128, 4, BATCH), 256, 0, stream>>>(VFP, VF, wkvd);
  g_x2ln<<<dim3(256, 1, BATCH), 256, 0, stream>>>(VF, M2, x, n2w, n2b, X2, Y2);
  g_win<<<dim3(512), 256, 0, stream>>>(Y2, win, Hpre);
  k_dwt<0, true, 340>
      <<<dim3(128, 11, BATCH), 256, 0, stream>>>(Hpre, Hg, wdw);
  g_out<<<dim3(512), 256, 0, stream>>>(Hg, wout, X2, out);
}

// Round 5
// 362.443 us; speedup vs baseline: 3.8075x; 3.4382x over previous
//
#include <hip/hip_runtime.h>
#include <hip/hip_bf16.h>
#include <math.h>

#define NPB 65536   // pixels per batch (256*256)
#define BATCH 2
#define NTOT (BATCH * NPB)   // 131072

typedef unsigned short u16;
typedef __attribute__((ext_vector_type(8))) short short8;
typedef __attribute__((ext_vector_type(4))) float f32x4;

// ---- channel-blocked pixel-major layout for all bf16 intermediates:
//   elem(cb, n, c) at  T[((size_t)cb * NTOT + n) * 16 + c],  c in [0,16)

__device__ __forceinline__ float bf2f(u16 u) {
  union { unsigned u; float f; } v; v.u = ((unsigned)u) << 16; return v.f;
}
__device__ __forceinline__ u16 f2bf(float f) {
  union { float f; unsigned u; } v; v.f = f;
  unsigned r = v.u + 0x7FFFu + ((v.u >> 16) & 1u);
  return (u16)(r >> 16);
}
__device__ __forceinline__ unsigned pk2(float a, float b) {
  return (unsigned)f2bf(a) | ((unsigned)f2bf(b) << 16);
}
__device__ __forceinline__ f32x4 mm(short8 a, short8 b, f32x4 c) {
  return __builtin_amdgcn_mfma_f32_16x16x32_bf16(a, b, c, 0, 0, 0);
}
__device__ __forceinline__ short8 afrag(const float* W, int ld, int row, int k0, int kval) {
  short8 r;
#pragma unroll
  for (int j = 0; j < 8; ++j) {
    float v = 0.f;
    if (row >= 0 && (k0 + j) < kval) v = W[(size_t)row * ld + k0 + j];
    r[j] = (short)f2bf(v);
  }
  return r;
}
__device__ __forceinline__ void st4(u16* p, f32x4 c) {
  uint2 v; v.x = pk2(c[0], c[1]); v.y = pk2(c[2], c[3]);
  *reinterpret_cast<uint2*>(p) = v;
}

// ---------------- K1: LN1, channel-major f32 -> blocked bf16 (4 blocks)
__global__ __launch_bounds__(256, 4) void k_ln1(
    const float* __restrict__ x, const float* __restrict__ n1w,
    const float* __restrict__ n1b, u16* __restrict__ Y1)
{
  const int n = blockIdx.x * 256 + threadIdx.x;
  const int b = blockIdx.y;
  const size_t pix = (size_t)b * NPB + n;
  const float* xb = x + ((size_t)b * 64) * NPB + n;
  float y[64];
  float mu = 0.f;
#pragma unroll
  for (int c = 0; c < 64; ++c) { y[c] = xb[(size_t)c * NPB]; mu += y[c]; }
  mu *= (1.f / 64.f);
  float var = 0.f;
#pragma unroll
  for (int c = 0; c < 64; ++c) { float d = y[c] - mu; var = fmaf(d, d, var); }
  const float rstd = rsqrtf(var * (1.f / 64.f) + 1e-5f);
#pragma unroll
  for (int c = 0; c < 64; ++c) y[c] = (y[c] - mu) * rstd * n1w[c] + n1b[c];
#pragma unroll
  for (int cb = 0; cb < 4; ++cb) {
    u16* dst = Y1 + ((size_t)cb * NTOT + pix) * 16;
    uint4 v0, v1;
    v0.x = pk2(y[cb*16+0],  y[cb*16+1]);  v0.y = pk2(y[cb*16+2],  y[cb*16+3]);
    v0.z = pk2(y[cb*16+4],  y[cb*16+5]);  v0.w = pk2(y[cb*16+6],  y[cb*16+7]);
    v1.x = pk2(y[cb*16+8],  y[cb*16+9]);  v1.y = pk2(y[cb*16+10], y[cb*16+11]);
    v1.z = pk2(y[cb*16+12], y[cb*16+13]); v1.w = pk2(y[cb*16+14], y[cb*16+15]);
    *reinterpret_cast<uint4*>(dst) = v0;
    *reinterpret_cast<uint4*>(dst + 8) = v1;
  }
}

// ---------------- G1: QKVp (12 blocks) = Wqkv(192x64) * Y1
__global__ __launch_bounds__(256, 2) void g_qkvp(
    const u16* __restrict__ Y1, const float* __restrict__ wq,
    u16* __restrict__ qkvp)
{
  const int l = threadIdx.x & 63, fr = l & 15, fq = l >> 4;
  const int wv = blockIdx.x * 4 + (threadIdx.x >> 6);
  const int nw = gridDim.x * 4;
  short8 A[12][2];
#pragma unroll
  for (int t = 0; t < 12; ++t)
#pragma unroll
    for (int kh = 0; kh < 2; ++kh)
      A[t][kh] = afrag(wq, 64, t * 16 + fr, kh * 32 + fq * 8, 64);
  const size_t hof = (size_t)(fq & 1) * 8;
  for (int tile = wv; tile < 8192; tile += nw) {
    const size_t n = (size_t)tile * 16 + fr;
    const short8 b0 = *reinterpret_cast<const short8*>(
        Y1 + (((size_t)(fq >> 1)) * NTOT + n) * 16 + hof);
    const short8 b1 = *reinterpret_cast<const short8*>(
        Y1 + (((size_t)(2 + (fq >> 1))) * NTOT + n) * 16 + hof);
    f32x4 c[12];
#pragma unroll
    for (int t = 0; t < 12; ++t) c[t] = f32x4{0.f, 0.f, 0.f, 0.f};
#pragma unroll
    for (int t = 0; t < 12; ++t) c[t] = mm(A[t][0], b0, c[t]);
#pragma unroll
    for (int t = 0; t < 12; ++t) c[t] = mm(A[t][1], b1, c[t]);
#pragma unroll
    for (int t = 0; t < 12; ++t)
      st4(qkvp + ((size_t)t * NTOT + n) * 16 + fq * 4, c[t]);
  }
}

// ---------------- register-rolling depthwise 3x3 SAME on blocked layout.
// Thread = (CH-channel unit q, x, vertical strip). No LDS, no barriers.
// GATE: plane0 = channel c in [0,176) (block c>>4), plane1 = block 11+(c>>4);
//       out = gelu(x1)*x2 at block c>>4. Non-gate: unit q of the tensor,
//       weight row = wofs + c.
template<int CH, bool GATE, int STRIP>
__global__ __launch_bounds__(256, 2) void k_dwr(
    const u16* __restrict__ in, u16* __restrict__ out,
    const float* __restrict__ wdw, int wofs)
{
  typedef short __attribute__((ext_vector_type(CH))) shortC;
  constexpr int NPL = GATE ? 2 : 1;
  const int x = threadIdx.x;
  const int q = blockIdx.x, strip = blockIdx.y, b = blockIdx.z;
  const int y0 = strip * STRIP;
  const int c0 = q * CH;
  const int cb0 = c0 >> 4, e0 = c0 & 15;

  const u16* pin[NPL];
  pin[0] = in + ((size_t)cb0 * NTOT + (size_t)b * NPB) * 16 + e0;
  if (GATE)
    pin[NPL - 1] = in + ((size_t)(11 + cb0) * NTOT + (size_t)b * NPB) * 16 + e0;

  float w[NPL][9][CH];
#pragma unroll
  for (int pl = 0; pl < NPL; ++pl)
#pragma unroll
    for (int ch = 0; ch < CH; ++ch) {
      const int c = c0 + ch;
      int row; bool valid;
      if (GATE) { valid = c < 170; row = pl * 170 + c; }
      else { valid = true; row = wofs + c; }
#pragma unroll
      for (int tap = 0; tap < 9; ++tap)
        w[pl][tap][ch] = valid ? wdw[(size_t)row * 9 + tap] : 0.f;
    }

  auto LD = [&](const u16* p, int yy, int xx) -> shortC {
    shortC v;
#pragma unroll
    for (int j = 0; j < CH; ++j) v[j] = 0;
    if ((unsigned)yy < 256u && (unsigned)xx < 256u)
      v = *reinterpret_cast<const shortC*>(p + (size_t)(yy * 256 + xx) * 16);
    return v;
  };

  shortC r[NPL][3][3];   // [plane][row: 0=y-1,1=y,2=y+1][dx]
#pragma unroll
  for (int pl = 0; pl < NPL; ++pl) {
    r[pl][0][0] = LD(pin[pl], y0 - 1, x - 1);
    r[pl][0][1] = LD(pin[pl], y0 - 1, x);
    r[pl][0][2] = LD(pin[pl], y0 - 1, x + 1);
    r[pl][1][0] = LD(pin[pl], y0, x - 1);
    r[pl][1][1] = LD(pin[pl], y0, x);
    r[pl][1][2] = LD(pin[pl], y0, x + 1);
  }

#pragma unroll 2
  for (int yy = 0; yy < STRIP; ++yy) {
    const int y = y0 + yy;
#pragma unroll
    for (int pl = 0; pl < NPL; ++pl) {
      r[pl][2][0] = LD(pin[pl], y + 1, x - 1);
      r[pl][2][1] = LD(pin[pl], y + 1, x);
      r[pl][2][2] = LD(pin[pl], y + 1, x + 1);
    }
    float acc[NPL][CH];
#pragma unroll
    for (int pl = 0; pl < NPL; ++pl)
#pragma unroll
      for (int ch = 0; ch < CH; ++ch) acc[pl][ch] = 0.f;
#pragma unroll
    for (int pl = 0; pl < NPL; ++pl)
#pragma unroll
      for (int ky = 0; ky < 3; ++ky)
#pragma unroll
        for (int kx = 0; kx < 3; ++kx)
#pragma unroll
          for (int ch = 0; ch < CH; ++ch)
            acc[pl][ch] = fmaf(w[pl][ky * 3 + kx][ch],
                               bf2f((u16)r[pl][ky][kx][ch]), acc[pl][ch]);

    float v[CH];
#pragma unroll
    for (int ch = 0; ch < CH; ++ch) {
      if (GATE) {
        const float a = acc[0][ch];
        v[ch] = 0.5f * a * (1.f + erff(a * 0.70710678118f)) * acc[NPL - 1][ch];
      } else {
        v[ch] = acc[0][ch];
      }
    }
    u16* po = out + ((size_t)cb0 * NTOT + (size_t)b * NPB +
                     (size_t)(y * 256 + x)) * 16 + e0;
    if constexpr (CH == 4) {
      uint2 o; o.x = pk2(v[0], v[1]); o.y = pk2(v[2], v[3]);
      *reinterpret_cast<uint2*>(po) = o;
    } else {
      uint4 o;
      o.x = pk2(v[0], v[1]); o.y = pk2(v[2], v[3]);
      o.z = pk2(v[4], v[5]); o.w = pk2(v[6], v[7]);
      *reinterpret_cast<uint4*>(po) = o;
    }
    // roll the window down
#pragma unroll
    for (int pl = 0; pl < NPL; ++pl)
#pragma unroll
      for (int dx = 0; dx < 3; ++dx) {
        r[pl][0][dx] = r[pl][1][dx];
        r[pl][1][dx] = r[pl][2][dx];
      }
  }
}

// ---------------- gram/norm partials via MFMA (blocked: q=block h, k=block 4+h)
__global__ __launch_bounds__(256, 2) void k_gram_p(
    const u16* __restrict__ qkv, float* __restrict__ part)
{
  __shared__ __align__(16) u16 lds[32][520];
  const int chunk = blockIdx.x, h = blockIdx.y, b = blockIdx.z;
  const int t = threadIdx.x;
#pragma unroll
  for (int i = 0; i < 2; ++i) {
    const int p = t + i * 256;
    const size_t pix = (size_t)b * NPB + chunk * 512 + p;
    const u16* srcq = qkv + ((size_t)h * NTOT + pix) * 16;
    const u16* srck = qkv + ((size_t)(4 + h) * NTOT + pix) * 16;
    const short8 q0 = *reinterpret_cast<const short8*>(srcq);
    const short8 q1 = *reinterpret_cast<const short8*>(srcq + 8);
    const short8 k0 = *reinterpret_cast<const short8*>(srck);
    const short8 k1 = *reinterpret_cast<const short8*>(srck + 8);
#pragma unroll
    for (int j = 0; j < 8; ++j) {
      lds[j][p] = (u16)q0[j];  lds[8 + j][p] = (u16)q1[j];
      lds[16 + j][p] = (u16)k0[j]; lds[24 + j][p] = (u16)k1[j];
    }
  }
  __syncthreads();
  const int w = t >> 6, l = t & 63, fr = l & 15, fq = l >> 4;
  if (w >= 3) return;
  float* pp = part + ((size_t)((b * 4 + h) * 128) + chunk) * 288;
  const int rowA = (w == 2) ? 16 + fr : fr;
  const int rowB = (w == 0) ? 16 + fr : rowA;
  f32x4 acc = {0.f, 0.f, 0.f, 0.f};
#pragma unroll
  for (int kt = 0; kt < 16; ++kt) {
    const short8 a  = *reinterpret_cast<const short8*>(&lds[rowA][kt * 32 + fq * 8]);
    const short8 bb = *reinterpret_cast<const short8*>(&lds[rowB][kt * 32 + fq * 8]);
    acc = mm(a, bb, acc);
  }
  if (w == 0) {
#pragma unroll
    for (int r = 0; r < 4; ++r) pp[(fq * 4 + r) * 16 + fr] = acc[r];
  } else if ((fr >> 2) == fq) {
    pp[(w == 1 ? 256 : 272) + fr] = acc[fr & 3];
  }
}

// ---------------- reduce partials over 128 chunks
__global__ __launch_bounds__(320) void k_gram_red(
    const float* __restrict__ part, float* __restrict__ G,
    float* __restrict__ Sq, float* __restrict__ Sk)
{
  const int bh = blockIdx.x;
  const int t = threadIdx.x;
  if (t >= 288) return;
  const float* p = part + (size_t)bh * 128 * 288 + t;
  float s = 0.f;
  for (int ch = 0; ch < 128; ++ch) s += p[(size_t)ch * 288];
  const int b = bh >> 2, h = bh & 3;
  if (t < 256) G[bh * 256 + t] = s;
  else if (t < 272) Sq[b * 64 + h * 16 + (t - 256)] = s;
  else Sk[b * 64 + h * 16 + (t - 272)] = s;
}

// ---------------- softmax + fold conv matrices (tiny, 1 block)
__global__ __launch_bounds__(256) void k_attn(
    const float* __restrict__ G, const float* __restrict__ Sq,
    const float* __restrict__ Sk, const float* __restrict__ temp,
    const float* __restrict__ wpo, const float* __restrict__ wkv,
    const float* __restrict__ wpof, float* __restrict__ P,
    float* __restrict__ M2)
{
  __shared__ float attn[BATCH][4][16][16];
  __shared__ float M1[BATCH][64][64];
  __shared__ float rq[128], rk[128];
  const int t = threadIdx.x;
  if (t < 128) {
    rq[t] = 1.f / fmaxf(sqrtf(Sq[t]), 1e-12f);
    rk[t] = 1.f / fmaxf(sqrtf(Sk[t]), 1e-12f);
  }
  __syncthreads();
  if (t < 128) {
    const int b = t >> 6, h = (t >> 4) & 3, d = t & 15;
    const float tm = temp[h];
    const float* g = G + ((b * 4 + h) * 16 + d) * 16;
    const float rqd = rq[b * 64 + h * 16 + d];
    float L[16], mx = -1e30f;
#pragma unroll
    for (int e = 0; e < 16; ++e) {
      L[e] = g[e] * rqd * rk[b * 64 + h * 16 + e] * tm;
      mx = fmaxf(mx, L[e]);
    }
    float s = 0.f;
#pragma unroll
    for (int e = 0; e < 16; ++e) { L[e] = expf(L[e] - mx); s += L[e]; }
    const float inv = 1.f / s;
#pragma unroll
    for (int e = 0; e < 16; ++e) attn[b][h][d][e] = L[e] * inv;
  }
  __syncthreads();
  for (int s0 = 0; s0 < 32; ++s0) {
    const int idx = t * 32 + s0;
    const int b = idx >> 12, o = (idx >> 6) & 63, c = idx & 63;
    const int h = c >> 4, e = c & 15;
    float a = 0.f;
#pragma unroll
    for (int d = 0; d < 16; ++d) a = fmaf(wpo[o * 64 + h * 16 + d], attn[b][h][d][e], a);
    M1[b][o][c] = a;
  }
  __syncthreads();
  for (int s0 = 0; s0 < 32; ++s0) {
    const int idx = t * 32 + s0;
    const int b = idx >> 12, o = (idx >> 6) & 63, c = idx & 63;
    const int h = c >> 4, e = c & 15;
    float a = 0.f;
    for (int j = 0; j < 64; ++j) a = fmaf(wkv[(64 + o) * 64 + j], M1[b][j][c], a);
    P[(b * 64 + o) * 64 + c] = a;
    float a2 = 0.f;
#pragma unroll
    for (int d = 0; d < 16; ++d) a2 = fmaf(wpof[o * 64 + h * 16 + d], attn[b][h][d][e], a2);
    M2[(b * 64 + o) * 64 + c] = a2;
  }
}

// ---------------- G2: VFP (4 blocks) = P_b * v (qkv blocks 8..11)
__global__ __launch_bounds__(256, 2) void g_pv(
    const u16* __restrict__ qkv, const float* __restrict__ P,
    u16* __restrict__ vfp)
{
  const int l = threadIdx.x & 63, fr = l & 15, fq = l >> 4;
  const int wv = blockIdx.x * 4 + (threadIdx.x >> 6);
  const int nw = gridDim.x * 4;
  const int b = blockIdx.z;
  const float* Pb = P + b * 4096;
  short8 A[4][2];
#pragma unroll
  for (int t = 0; t < 4; ++t)
#pragma unroll
    for (int kh = 0; kh < 2; ++kh)
      A[t][kh] = afrag(Pb, 64, t * 16 + fr, kh * 32 + fq * 8, 64);
  const size_t hof = (size_t)(fq & 1) * 8;
  for (int tile = wv; tile < 4096; tile += nw) {
    const size_t n = (size_t)b * NPB + (size_t)tile * 16 + fr;
    const short8 b0 = *reinterpret_cast<const short8*>(
        qkv + ((size_t)(8 + (fq >> 1)) * NTOT + n) * 16 + hof);
    const short8 b1 = *reinterpret_cast<const short8*>(
        qkv + ((size_t)(10 + (fq >> 1)) * NTOT + n) * 16 + hof);
    f32x4 c[4];
#pragma unroll
    for (int t = 0; t < 4; ++t) c[t] = f32x4{0.f, 0.f, 0.f, 0.f};
#pragma unroll
    for (int t = 0; t < 4; ++t) c[t] = mm(A[t][0], b0, c[t]);
#pragma unroll
    for (int t = 0; t < 4; ++t) c[t] = mm(A[t][1], b1, c[t]);
#pragma unroll
    for (int t = 0; t < 4; ++t)
      st4(vfp + ((size_t)t * NTOT + n) * 16 + fq * 4, c[t]);
  }
}

// ---------------- G3 fused: X2 = x + M2_b*vf (bf16); Y2 = LN2(X2)
__global__ __launch_bounds__(256, 2) void g_x2ln(
    const u16* __restrict__ vf, const float* __restrict__ M2,
    const float* __restrict__ x, const float* __restrict__ n2w,
    const float* __restrict__ n2b, u16* __restrict__ X2,
    u16* __restrict__ Y2)
{
  const int l = threadIdx.x & 63, fr = l & 15, fq = l >> 4;
  const int wv = blockIdx.x * 4 + (threadIdx.x >> 6);
  const int nw = gridDim.x * 4;
  const int b = blockIdx.z;
  const float* Mb = M2 + b * 4096;
  short8 A[4][2];
#pragma unroll
  for (int t = 0; t < 4; ++t)
#pragma unroll
    for (int kh = 0; kh < 2; ++kh)
      A[t][kh] = afrag(Mb, 64, t * 16 + fr, kh * 32 + fq * 8, 64);
  const size_t hof = (size_t)(fq & 1) * 8;
  for (int tile = wv; tile < 4096; tile += nw) {
    const int pix0 = tile * 16;
    const size_t n = (size_t)b * NPB + pix0 + fr;
    const short8 b0 = *reinterpret_cast<const short8*>(
        vf + ((size_t)(fq >> 1) * NTOT + n) * 16 + hof);
    const short8 b1 = *reinterpret_cast<const short8*>(
        vf + ((size_t)(2 + (fq >> 1)) * NTOT + n) * 16 + hof);
    f32x4 c[4];
#pragma unroll
    for (int t = 0; t < 4; ++t) c[t] = f32x4{0.f, 0.f, 0.f, 0.f};
#pragma unroll
    for (int t = 0; t < 4; ++t) c[t] = mm(A[t][0], b0, c[t]);
#pragma unroll
    for (int t = 0; t < 4; ++t) c[t] = mm(A[t][1], b1, c[t]);
    const int pix = pix0 + fr;
#pragma unroll
    for (int t = 0; t < 4; ++t)
#pragma unroll
      for (int r = 0; r < 4; ++r)
        c[t][r] += x[((size_t)(b * 64 + t * 16 + fq * 4 + r)) * NPB + pix];
#pragma unroll
    for (int t = 0; t < 4; ++t)
      st4(X2 + ((size_t)t * NTOT + n) * 16 + fq * 4, c[t]);
    float s = 0.f;
#pragma unroll
    for (int t = 0; t < 4; ++t)
#pragma unroll
      for (int r = 0; r < 4; ++r) s += c[t][r];
    s += __shfl_xor(s, 16); s += __shfl_xor(s, 32);
    const float mu = s * (1.f / 64.f);
    float ss = 0.f;
#pragma unroll
    for (int t = 0; t < 4; ++t)
#pragma unroll
      for (int r = 0; r < 4; ++r) { float d = c[t][r] - mu; ss = fmaf(d, d, ss); }
    ss += __shfl_xor(ss, 16); ss += __shfl_xor(ss, 32);
    const float rstd = rsqrtf(ss * (1.f / 64.f) + 1e-5f);
#pragma unroll
    for (int t = 0; t < 4; ++t)
#pragma unroll
      for (int r = 0; r < 4; ++r) {
        const int oc = t * 16 + fq * 4 + r;
        c[t][r] = (c[t][r] - mu) * rstd * n2w[oc] + n2b[oc];
      }
#pragma unroll
    for (int t = 0; t < 4; ++t)
      st4(Y2 + ((size_t)t * NTOT + n) * 16 + fq * 4, c[t]);
  }
}

// ---------------- G4: Hpre (22 blocks) = Win(340x64 padded) * Y2
__global__ __launch_bounds__(256, 2) void g_win(
    const u16* __restrict__ Y2, const float* __restrict__ win,
    u16* __restrict__ hpre)
{
  const int l = threadIdx.x & 63, fr = l & 15, fq = l >> 4;
  const int wv = blockIdx.x * 4 + (threadIdx.x >> 6);
  const int nw = gridDim.x * 4;
  const int half = wv & 1;
  short8 A[11][2];
#pragma unroll
  for (int t = 0; t < 11; ++t)
#pragma unroll
    for (int kh = 0; kh < 2; ++kh) {
      const int col = half * 176 + t * 16 + fr;
      const int row = col < 170 ? col : (col < 176 ? -1 : (col < 346 ? col - 6 : -1));
      A[t][kh] = afrag(win, 64, row, kh * 32 + fq * 8, 64);
    }
  const size_t hof = (size_t)(fq & 1) * 8;
  for (int tile = wv >> 1; tile < 8192; tile += (nw >> 1)) {
    const size_t n = (size_t)tile * 16 + fr;
    const short8 b0 = *reinterpret_cast<const short8*>(
        Y2 + ((size_t)(fq >> 1) * NTOT + n) * 16 + hof);
    const short8 b1 = *reinterpret_cast<const short8*>(
        Y2 + ((size_t)(2 + (fq >> 1)) * NTOT + n) * 16 + hof);
    f32x4 c[11];
#pragma unroll
    for (int t = 0; t < 11; ++t) c[t] = f32x4{0.f, 0.f, 0.f, 0.f};
#pragma unroll
    for (int t = 0; t < 11; ++t) c[t] = mm(A[t][0], b0, c[t]);
#pragma unroll
    for (int t = 0; t < 11; ++t) c[t] = mm(A[t][1], b1, c[t]);
#pragma unroll
    for (int t = 0; t < 11; ++t)
      st4(hpre + ((size_t)(half * 11 + t) * NTOT + n) * 16 + fq * 4, c[t]);
  }
}

// ---------------- G5: out = X2 + Wout(64x170) * Hg (11 blocks)
__global__ __launch_bounds__(256, 2) void g_out(
    const u16* __restrict__ hg, const float* __restrict__ wout,
    const u16* __restrict__ X2, float* __restrict__ out)
{
  const int l = threadIdx.x & 63, fr = l & 15, fq = l >> 4;
  const int wv = blockIdx.x * 4 + (threadIdx.x >> 6);
  const int nw = gridDim.x * 4;
  short8 A[4][6];
#pragma unroll
  for (int t = 0; t < 4; ++t)
#pragma unroll
    for (int kh = 0; kh < 6; ++kh)
      A[t][kh] = afrag(wout, 170, t * 16 + fr, kh * 32 + fq * 8, 170);
  const size_t hof = (size_t)(fq & 1) * 8;
  for (int tile = wv; tile < 8192; tile += nw) {
    const size_t n = (size_t)tile * 16 + fr;
    f32x4 c[4];
#pragma unroll
    for (int t = 0; t < 4; ++t) c[t] = f32x4{0.f, 0.f, 0.f, 0.f};
#pragma unroll
    for (int kh = 0; kh < 6; ++kh) {
      int hb = kh * 2 + (fq >> 1);
      if (hb > 10) hb = 10;  // k>=170 weights are zero; value irrelevant
      const short8 bb = *reinterpret_cast<const short8*>(
          hg + ((size_t)hb * NTOT + n) * 16 + hof);
#pragma unroll
      for (int t = 0; t < 4; ++t) c[t] = mm(A[t][kh], bb, c[t]);
    }
    const int b = (int)(n >> 16);
    const int pix = (int)(n & 65535);
#pragma unroll
    for (int t = 0; t < 4; ++t) {
      const uint2 xv = *reinterpret_cast<const uint2*>(
          X2 + ((size_t)t * NTOT + n) * 16 + fq * 4);
      const u16 h0 = (u16)(xv.x & 0xffff), h1 = (u16)(xv.x >> 16);
      const u16 h2 = (u16)(xv.y & 0xffff), h3 = (u16)(xv.y >> 16);
      const int ocb = b * 64 + t * 16 + fq * 4;
      out[((size_t)(ocb + 0)) * NPB + pix] = c[t][0] + bf2f(h0);
      out[((size_t)(ocb + 1)) * NPB + pix] = c[t][1] + bf2f(h1);
      out[((size_t)(ocb + 2)) * NPB + pix] = c[t][2] + bf2f(h2);
      out[((size_t)(ocb + 3)) * NPB + pix] = c[t][3] + bf2f(h3);
    }
  }
}

extern "C" void kernel_launch(void* const* d_in, const int* in_sizes, int n_in,
                              void* d_out, int out_size, void* d_ws, size_t ws_size,
                              hipStream_t stream)
{
  const float* x     = (const float*)d_in[0];
  const float* n1w   = (const float*)d_in[1];
  const float* n1b   = (const float*)d_in[2];
  const float* temp  = (const float*)d_in[3];
  const float* wqkv  = (const float*)d_in[4];
  const float* wqkvd = (const float*)d_in[5];
  const float* wpo   = (const float*)d_in[6];
  const float* wkv   = (const float*)d_in[7];
  const float* wkvd  = (const float*)d_in[8];
  const float* wpof  = (const float*)d_in[9];
  const float* n2w   = (const float*)d_in[10];
  const float* n2b   = (const float*)d_in[11];
  const float* win   = (const float*)d_in[12];
  const float* wdw   = (const float*)d_in[13];
  const float* wout  = (const float*)d_in[14];
  float* out = (float*)d_out;

  char* ws = (char*)d_ws;
  const size_t offA  = 0;                       // 16.78 MB: Y1 / VFP / Y2
  const size_t offB  = 16777216;                // 50.33 MB: QKVp / VF / Hpre(start)
  const size_t offC  = offB + 50331648;         // 50.33 MB: QKV / Hpre(cont)
  const size_t offHg = offC + 50331648;         // 46.14 MB (11 blocks exactly)
  const size_t offX2 = offHg + 46137344 + 256;  // 16.78 MB
  const size_t offSm = offX2 + 16777216;

  u16* Y1   = (u16*)(ws + offA);
  u16* VFP  = (u16*)(ws + offA);
  u16* Y2   = (u16*)(ws + offA);
  u16* QKVp = (u16*)(ws + offB);
  u16* VF   = (u16*)(ws + offB);
  u16* Hpre = (u16*)(ws + offB);   // 22 blocks span B+C (92.3 MB <= 100.7 MB)
  u16* QKV  = (u16*)(ws + offC);
  u16* Hg   = (u16*)(ws + offHg);
  u16* X2   = (u16*)(ws + offX2);
  float* part = (float*)(ws + offSm);                     // 1,179,648 B
  float* G    = (float*)(ws + offSm + 1179648);           // 8 KB
  float* Sq   = (float*)(ws + offSm + 1179648 + 8192);    // 512 B
  float* Sk   = (float*)(ws + offSm + 1179648 + 8704);    // 512 B
  float* P    = (float*)(ws + offSm + 1179648 + 9216);    // 32 KB
  float* M2   = (float*)(ws + offSm + 1179648 + 41984);   // 32 KB

  k_ln1<<<dim3(NPB / 256, BATCH), 256, 0, stream>>>(x, n1w, n1b, Y1);
  g_qkvp<<<dim3(512), 256, 0, stream>>>(Y1, wqkv, QKVp);
  // dw 192ch: 24 8-ch units x 16 strips x 2 batches
  k_dwr<8, false, 16><<<dim3(24, 16, BATCH), 256, 0, stream>>>(QKVp, QKV, wqkvd, 0);
  k_gram_p<<<dim3(128, 4, BATCH), 256, 0, stream>>>(QKV, part);
  k_gram_red<<<dim3(BATCH * 4), 320, 0, stream>>>(part, G, Sq, Sk);
  k_attn<<<dim3(1), 256, 0, stream>>>(G, Sq, Sk, temp, wpo, wkv, wpof, P, M2);
  g_pv<<<dim3(256, 1, BATCH), 256, 0, stream>>>(QKV, P, VFP);
  // dw 64ch (kv branch, weight rows 64..127): 8 units x 32 strips
  k_dwr<8, false, 8><<<dim3(8, 32, BATCH), 256, 0, stream>>>(VFP, VF, wkvd, 64);
  g_x2ln<<<dim3(256, 1, BATCH), 256, 0, stream>>>(VF, M2, x, n2w, n2b, X2, Y2);
  g_win<<<dim3(512), 256, 0, stream>>>(Y2, win, Hpre);
  // gated dw 352->176: 44 4-ch units x 16 strips x 2 batches
  k_dwr<4, true, 16><<<dim3(44, 16, BATCH), 256, 0, stream>>>(Hpre, Hg, wdw, 0);
  g_out<<<dim3(512), 256, 0, stream>>>(Hg, wout, X2, out);
}

// Round 6
// 287.255 us; speedup vs baseline: 4.8041x; 1.2617x over previous
//
#include <hip/hip_runtime.h>
#include <hip/hip_bf16.h>
#include <math.h>

#define NPB 65536   // pixels per batch (256*256)
#define BATCH 2
#define NTOT (BATCH * NPB)   // 131072

typedef unsigned short u16;
typedef __attribute__((ext_vector_type(8))) short short8;
typedef __attribute__((ext_vector_type(4))) float f32x4;

// ---- channel-blocked pixel-major layout for all bf16 intermediates:
//   elem(cb, n, c) at  T[((size_t)cb * NTOT + n) * 16 + c],  c in [0,16)

__device__ __forceinline__ float bf2f(u16 u) {
  union { unsigned u; float f; } v; v.u = ((unsigned)u) << 16; return v.f;
}
__device__ __forceinline__ u16 f2bf(float f) {
  union { float f; unsigned u; } v; v.f = f;
  unsigned r = v.u + 0x7FFFu + ((v.u >> 16) & 1u);
  return (u16)(r >> 16);
}
__device__ __forceinline__ unsigned pk2(float a, float b) {
  return (unsigned)f2bf(a) | ((unsigned)f2bf(b) << 16);
}
__device__ __forceinline__ f32x4 mm(short8 a, short8 b, f32x4 c) {
  return __builtin_amdgcn_mfma_f32_16x16x32_bf16(a, b, c, 0, 0, 0);
}
__device__ __forceinline__ short8 afrag(const float* W, int ld, int row, int k0, int kval) {
  short8 r;
#pragma unroll
  for (int j = 0; j < 8; ++j) {
    float v = 0.f;
    if (row >= 0 && (k0 + j) < kval) v = W[(size_t)row * ld + k0 + j];
    r[j] = (short)f2bf(v);
  }
  return r;
}
__device__ __forceinline__ void st4(u16* p, f32x4 c) {
  uint2 v; v.x = pk2(c[0], c[1]); v.y = pk2(c[2], c[3]);
  *reinterpret_cast<uint2*>(p) = v;
}

// ---------------- K1: LN1, channel-major f32 -> blocked bf16 (4 blocks)
__global__ __launch_bounds__(256, 4) void k_ln1(
    const float* __restrict__ x, const float* __restrict__ n1w,
    const float* __restrict__ n1b, u16* __restrict__ Y1)
{
  const int n = blockIdx.x * 256 + threadIdx.x;
  const int b = blockIdx.y;
  const size_t pix = (size_t)b * NPB + n;
  const float* xb = x + ((size_t)b * 64) * NPB + n;
  float y[64];
  float mu = 0.f;
#pragma unroll
  for (int c = 0; c < 64; ++c) { y[c] = xb[(size_t)c * NPB]; mu += y[c]; }
  mu *= (1.f / 64.f);
  float var = 0.f;
#pragma unroll
  for (int c = 0; c < 64; ++c) { float d = y[c] - mu; var = fmaf(d, d, var); }
  const float rstd = rsqrtf(var * (1.f / 64.f) + 1e-5f);
#pragma unroll
  for (int c = 0; c < 64; ++c) y[c] = (y[c] - mu) * rstd * n1w[c] + n1b[c];
#pragma unroll
  for (int cb = 0; cb < 4; ++cb) {
    u16* dst = Y1 + ((size_t)cb * NTOT + pix) * 16;
    uint4 v0, v1;
    v0.x = pk2(y[cb*16+0],  y[cb*16+1]);  v0.y = pk2(y[cb*16+2],  y[cb*16+3]);
    v0.z = pk2(y[cb*16+4],  y[cb*16+5]);  v0.w = pk2(y[cb*16+6],  y[cb*16+7]);
    v1.x = pk2(y[cb*16+8],  y[cb*16+9]);  v1.y = pk2(y[cb*16+10], y[cb*16+11]);
    v1.z = pk2(y[cb*16+12], y[cb*16+13]); v1.w = pk2(y[cb*16+14], y[cb*16+15]);
    *reinterpret_cast<uint4*>(dst) = v0;
    *reinterpret_cast<uint4*>(dst + 8) = v1;
  }
}

// ---------------- G1: QKVp (12 blocks) = Wqkv(192x64) * Y1
__global__ __launch_bounds__(256, 2) void g_qkvp(
    const u16* __restrict__ Y1, const float* __restrict__ wq,
    u16* __restrict__ qkvp)
{
  const int l = threadIdx.x & 63, fr = l & 15, fq = l >> 4;
  const int wv = blockIdx.x * 4 + (threadIdx.x >> 6);
  const int nw = gridDim.x * 4;
  short8 A[12][2];
#pragma unroll
  for (int t = 0; t < 12; ++t)
#pragma unroll
    for (int kh = 0; kh < 2; ++kh)
      A[t][kh] = afrag(wq, 64, t * 16 + fr, kh * 32 + fq * 8, 64);
  const size_t hof = (size_t)(fq & 1) * 8;
  for (int tile = wv; tile < 8192; tile += nw) {
    const size_t n = (size_t)tile * 16 + fr;
    const short8 b0 = *reinterpret_cast<const short8*>(
        Y1 + (((size_t)(fq >> 1)) * NTOT + n) * 16 + hof);
    const short8 b1 = *reinterpret_cast<const short8*>(
        Y1 + (((size_t)(2 + (fq >> 1))) * NTOT + n) * 16 + hof);
    f32x4 c[12];
#pragma unroll
    for (int t = 0; t < 12; ++t) c[t] = f32x4{0.f, 0.f, 0.f, 0.f};
#pragma unroll
    for (int t = 0; t < 12; ++t) c[t] = mm(A[t][0], b0, c[t]);
#pragma unroll
    for (int t = 0; t < 12; ++t) c[t] = mm(A[t][1], b1, c[t]);
#pragma unroll
    for (int t = 0; t < 12; ++t)
      st4(qkvp + ((size_t)t * NTOT + n) * 16 + fq * 4, c[t]);
  }
}

// ---------------- register-rolling depthwise 3x3 SAME on blocked layout.
// Lane map: sub = tid % (16/CH) covers channel sub-unit of ONE pixel,
// xi = tid / (16/CH) is the pixel x within the block's span -> every wave
// load/store is a dense contiguous 512B span. No LDS, no barriers.
// GATE: plane0 = block q (x1), plane1 = block 11+q (x2); out = gelu(x1)*x2.
template<int CH, bool GATE, int STRIP>
__global__ __launch_bounds__(256, 2) void k_dwr(
    const u16* __restrict__ in, u16* __restrict__ out,
    const float* __restrict__ wdw, int wofs)
{
  typedef short __attribute__((ext_vector_type(CH))) shortC;
  constexpr int NPL = GATE ? 2 : 1;
  constexpr int LPP = 16 / CH;        // lanes per pixel
  constexpr int NX  = 256 / LPP;      // pixels per block in x
  constexpr int XC  = 256 / NX;       // x-chunks per row
  const int t = threadIdx.x;
  const int sub = t % LPP, xi = t / LPP;
  const int q = blockIdx.x / XC, xc = blockIdx.x % XC;
  const int strip = blockIdx.y, b = blockIdx.z;
  const int x = xc * NX + xi;
  const int y0 = strip * STRIP;
  const int e0 = sub * CH;
  const int c0 = q * 16 + e0;

  const u16* pin[NPL];
  pin[0] = in + ((size_t)q * NTOT + (size_t)b * NPB) * 16 + e0;
  if (GATE)
    pin[NPL - 1] = in + ((size_t)(11 + q) * NTOT + (size_t)b * NPB) * 16 + e0;

  float w[NPL][9][CH];
#pragma unroll
  for (int pl = 0; pl < NPL; ++pl)
#pragma unroll
    for (int ch = 0; ch < CH; ++ch) {
      const int c = c0 + ch;
      int row; bool valid;
      if (GATE) { valid = c < 170; row = pl * 170 + c; }
      else { valid = true; row = wofs + c; }
#pragma unroll
      for (int tap = 0; tap < 9; ++tap)
        w[pl][tap][ch] = valid ? wdw[(size_t)row * 9 + tap] : 0.f;
    }

  auto LD = [&](const u16* p, int yy, int xx) -> shortC {
    shortC v;
#pragma unroll
    for (int j = 0; j < CH; ++j) v[j] = 0;
    if ((unsigned)yy < 256u && (unsigned)xx < 256u)
      v = *reinterpret_cast<const shortC*>(p + (size_t)(yy * 256 + xx) * 16);
    return v;
  };

  shortC r[NPL][3][3];   // [plane][row: 0=y-1,1=y,2=y+1][dx]
#pragma unroll
  for (int pl = 0; pl < NPL; ++pl) {
    r[pl][0][0] = LD(pin[pl], y0 - 1, x - 1);
    r[pl][0][1] = LD(pin[pl], y0 - 1, x);
    r[pl][0][2] = LD(pin[pl], y0 - 1, x + 1);
    r[pl][1][0] = LD(pin[pl], y0, x - 1);
    r[pl][1][1] = LD(pin[pl], y0, x);
    r[pl][1][2] = LD(pin[pl], y0, x + 1);
  }

#pragma unroll 2
  for (int yy = 0; yy < STRIP; ++yy) {
    const int y = y0 + yy;
#pragma unroll
    for (int pl = 0; pl < NPL; ++pl) {
      r[pl][2][0] = LD(pin[pl], y + 1, x - 1);
      r[pl][2][1] = LD(pin[pl], y + 1, x);
      r[pl][2][2] = LD(pin[pl], y + 1, x + 1);
    }
    float acc[NPL][CH];
#pragma unroll
    for (int pl = 0; pl < NPL; ++pl)
#pragma unroll
      for (int ch = 0; ch < CH; ++ch) acc[pl][ch] = 0.f;
#pragma unroll
    for (int pl = 0; pl < NPL; ++pl)
#pragma unroll
      for (int ky = 0; ky < 3; ++ky)
#pragma unroll
        for (int kx = 0; kx < 3; ++kx)
#pragma unroll
          for (int ch = 0; ch < CH; ++ch)
            acc[pl][ch] = fmaf(w[pl][ky * 3 + kx][ch],
                               bf2f((u16)r[pl][ky][kx][ch]), acc[pl][ch]);

    float v[CH];
#pragma unroll
    for (int ch = 0; ch < CH; ++ch) {
      if (GATE) {
        const float a = acc[0][ch];
        v[ch] = 0.5f * a * (1.f + erff(a * 0.70710678118f)) * acc[NPL - 1][ch];
      } else {
        v[ch] = acc[0][ch];
      }
    }
    u16* po = out + ((size_t)q * NTOT + (size_t)b * NPB +
                     (size_t)(y * 256 + x)) * 16 + e0;
    if constexpr (CH == 4) {
      uint2 o; o.x = pk2(v[0], v[1]); o.y = pk2(v[2], v[3]);
      *reinterpret_cast<uint2*>(po) = o;
    } else {
      uint4 o;
      o.x = pk2(v[0], v[1]); o.y = pk2(v[2], v[3]);
      o.z = pk2(v[4], v[5]); o.w = pk2(v[6], v[7]);
      *reinterpret_cast<uint4*>(po) = o;
    }
    // roll the window down
#pragma unroll
    for (int pl = 0; pl < NPL; ++pl)
#pragma unroll
      for (int dx = 0; dx < 3; ++dx) {
        r[pl][0][dx] = r[pl][1][dx];
        r[pl][1][dx] = r[pl][2][dx];
      }
  }
}

// ---------------- gram/norm partials via MFMA (blocked: q=block h, k=block 4+h)
__global__ __launch_bounds__(256, 2) void k_gram_p(
    const u16* __restrict__ qkv, float* __restrict__ part)
{
  __shared__ __align__(16) u16 lds[32][520];
  const int chunk = blockIdx.x, h = blockIdx.y, b = blockIdx.z;
  const int t = threadIdx.x;
#pragma unroll
  for (int i = 0; i < 2; ++i) {
    const int p = t + i * 256;
    const size_t pix = (size_t)b * NPB + chunk * 512 + p;
    const u16* srcq = qkv + ((size_t)h * NTOT + pix) * 16;
    const u16* srck = qkv + ((size_t)(4 + h) * NTOT + pix) * 16;
    const short8 q0 = *reinterpret_cast<const short8*>(srcq);
    const short8 q1 = *reinterpret_cast<const short8*>(srcq + 8);
    const short8 k0 = *reinterpret_cast<const short8*>(srck);
    const short8 k1 = *reinterpret_cast<const short8*>(srck + 8);
#pragma unroll
    for (int j = 0; j < 8; ++j) {
      lds[j][p] = (u16)q0[j];  lds[8 + j][p] = (u16)q1[j];
      lds[16 + j][p] = (u16)k0[j]; lds[24 + j][p] = (u16)k1[j];
    }
  }
  __syncthreads();
  const int w = t >> 6, l = t & 63, fr = l & 15, fq = l >> 4;
  if (w >= 3) return;
  float* pp = part + ((size_t)((b * 4 + h) * 128) + chunk) * 288;
  const int rowA = (w == 2) ? 16 + fr : fr;
  const int rowB = (w == 0) ? 16 + fr : rowA;
  f32x4 acc = {0.f, 0.f, 0.f, 0.f};
#pragma unroll
  for (int kt = 0; kt < 16; ++kt) {
    const short8 a  = *reinterpret_cast<const short8*>(&lds[rowA][kt * 32 + fq * 8]);
    const short8 bb = *reinterpret_cast<const short8*>(&lds[rowB][kt * 32 + fq * 8]);
    acc = mm(a, bb, acc);
  }
  if (w == 0) {
#pragma unroll
    for (int r = 0; r < 4; ++r) pp[(fq * 4 + r) * 16 + fr] = acc[r];
  } else if ((fr >> 2) == fq) {
    pp[(w == 1 ? 256 : 272) + fr] = acc[fr & 3];
  }
}

// ---------------- reduce partials over 128 chunks
__global__ __launch_bounds__(320) void k_gram_red(
    const float* __restrict__ part, float* __restrict__ G,
    float* __restrict__ Sq, float* __restrict__ Sk)
{
  const int bh = blockIdx.x;
  const int t = threadIdx.x;
  if (t >= 288) return;
  const float* p = part + (size_t)bh * 128 * 288 + t;
  float s = 0.f;
  for (int ch = 0; ch < 128; ++ch) s += p[(size_t)ch * 288];
  const int b = bh >> 2, h = bh & 3;
  if (t < 256) G[bh * 256 + t] = s;
  else if (t < 272) Sq[b * 64 + h * 16 + (t - 256)] = s;
  else Sk[b * 64 + h * 16 + (t - 272)] = s;
}

// ---------------- softmax + fold conv matrices (tiny, 1 block)
__global__ __launch_bounds__(256) void k_attn(
    const float* __restrict__ G, const float* __restrict__ Sq,
    const float* __restrict__ Sk, const float* __restrict__ temp,
    const float* __restrict__ wpo, const float* __restrict__ wkv,
    const float* __restrict__ wpof, float* __restrict__ P,
    float* __restrict__ M2)
{
  __shared__ float attn[BATCH][4][16][16];
  __shared__ float M1[BATCH][64][64];
  __shared__ float rq[128], rk[128];
  const int t = threadIdx.x;
  if (t < 128) {
    rq[t] = 1.f / fmaxf(sqrtf(Sq[t]), 1e-12f);
    rk[t] = 1.f / fmaxf(sqrtf(Sk[t]), 1e-12f);
  }
  __syncthreads();
  if (t < 128) {
    const int b = t >> 6, h = (t >> 4) & 3, d = t & 15;
    const float tm = temp[h];
    const float* g = G + ((b * 4 + h) * 16 + d) * 16;
    const float rqd = rq[b * 64 + h * 16 + d];
    float L[16], mx = -1e30f;
#pragma unroll
    for (int e = 0; e < 16; ++e) {
      L[e] = g[e] * rqd * rk[b * 64 + h * 16 + e] * tm;
      mx = fmaxf(mx, L[e]);
    }
    float s = 0.f;
#pragma unroll
    for (int e = 0; e < 16; ++e) { L[e] = expf(L[e] - mx); s += L[e]; }
    const float inv = 1.f / s;
#pragma unroll
    for (int e = 0; e < 16; ++e) attn[b][h][d][e] = L[e] * inv;
  }
  __syncthreads();
  for (int s0 = 0; s0 < 32; ++s0) {
    const int idx = t * 32 + s0;
    const int b = idx >> 12, o = (idx >> 6) & 63, c = idx & 63;
    const int h = c >> 4, e = c & 15;
    float a = 0.f;
#pragma unroll
    for (int d = 0; d < 16; ++d) a = fmaf(wpo[o * 64 + h * 16 + d], attn[b][h][d][e], a);
    M1[b][o][c] = a;
  }
  __syncthreads();
  for (int s0 = 0; s0 < 32; ++s0) {
    const int idx = t * 32 + s0;
    const int b = idx >> 12, o = (idx >> 6) & 63, c = idx & 63;
    const int h = c >> 4, e = c & 15;
    float a = 0.f;
    for (int j = 0; j < 64; ++j) a = fmaf(wkv[(64 + o) * 64 + j], M1[b][j][c], a);
    P[(b * 64 + o) * 64 + c] = a;
    float a2 = 0.f;
#pragma unroll
    for (int d = 0; d < 16; ++d) a2 = fmaf(wpof[o * 64 + h * 16 + d], attn[b][h][d][e], a2);
    M2[(b * 64 + o) * 64 + c] = a2;
  }
}

// ---------------- G2: VFP (4 blocks) = P_b * v (qkv blocks 8..11)
__global__ __launch_bounds__(256, 2) void g_pv(
    const u16* __restrict__ qkv, const float* __restrict__ P,
    u16* __restrict__ vfp)
{
  const int l = threadIdx.x & 63, fr = l & 15, fq = l >> 4;
  const int wv = blockIdx.x * 4 + (threadIdx.x >> 6);
  const int nw = gridDim.x * 4;
  const int b = blockIdx.z;
  const float* Pb = P + b * 4096;
  short8 A[4][2];
#pragma unroll
  for (int t = 0; t < 4; ++t)
#pragma unroll
    for (int kh = 0; kh < 2; ++kh)
      A[t][kh] = afrag(Pb, 64, t * 16 + fr, kh * 32 + fq * 8, 64);
  const size_t hof = (size_t)(fq & 1) * 8;
  for (int tile = wv; tile < 4096; tile += nw) {
    const size_t n = (size_t)b * NPB + (size_t)tile * 16 + fr;
    const short8 b0 = *reinterpret_cast<const short8*>(
        qkv + ((size_t)(8 + (fq >> 1)) * NTOT + n) * 16 + hof);
    const short8 b1 = *reinterpret_cast<const short8*>(
        qkv + ((size_t)(10 + (fq >> 1)) * NTOT + n) * 16 + hof);
    f32x4 c[4];
#pragma unroll
    for (int t = 0; t < 4; ++t) c[t] = f32x4{0.f, 0.f, 0.f, 0.f};
#pragma unroll
    for (int t = 0; t < 4; ++t) c[t] = mm(A[t][0], b0, c[t]);
#pragma unroll
    for (int t = 0; t < 4; ++t) c[t] = mm(A[t][1], b1, c[t]);
#pragma unroll
    for (int t = 0; t < 4; ++t)
      st4(vfp + ((size_t)t * NTOT + n) * 16 + fq * 4, c[t]);
  }
}

// ---------------- G3 fused: X2 = x + M2_b*vf (bf16); Y2 = LN2(X2)
__global__ __launch_bounds__(256, 2) void g_x2ln(
    const u16* __restrict__ vf, const float* __restrict__ M2,
    const float* __restrict__ x, const float* __restrict__ n2w,
    const float* __restrict__ n2b, u16* __restrict__ X2,
    u16* __restrict__ Y2)
{
  const int l = threadIdx.x & 63, fr = l & 15, fq = l >> 4;
  const int wv = blockIdx.x * 4 + (threadIdx.x >> 6);
  const int nw = gridDim.x * 4;
  const int b = blockIdx.z;
  const float* Mb = M2 + b * 4096;
  short8 A[4][2];
#pragma unroll
  for (int t = 0; t < 4; ++t)
#pragma unroll
    for (int kh = 0; kh < 2; ++kh)
      A[t][kh] = afrag(Mb, 64, t * 16 + fr, kh * 32 + fq * 8, 64);
  const size_t hof = (size_t)(fq & 1) * 8;
  for (int tile = wv; tile < 4096; tile += nw) {
    const int pix0 = tile * 16;
    const size_t n = (size_t)b * NPB + pix0 + fr;
    const short8 b0 = *reinterpret_cast<const short8*>(
        vf + ((size_t)(fq >> 1) * NTOT + n) * 16 + hof);
    const short8 b1 = *reinterpret_cast<const short8*>(
        vf + ((size_t)(2 + (fq >> 1)) * NTOT + n) * 16 + hof);
    f32x4 c[4];
#pragma unroll
    for (int t = 0; t < 4; ++t) c[t] = f32x4{0.f, 0.f, 0.f, 0.f};
#pragma unroll
    for (int t = 0; t < 4; ++t) c[t] = mm(A[t][0], b0, c[t]);
#pragma unroll
    for (int t = 0; t < 4; ++t) c[t] = mm(A[t][1], b1, c[t]);
    const int pix = pix0 + fr;
#pragma unroll
    for (int t = 0; t < 4; ++t)
#pragma unroll
      for (int r = 0; r < 4; ++r)
        c[t][r] += x[((size_t)(b * 64 + t * 16 + fq * 4 + r)) * NPB + pix];
#pragma unroll
    for (int t = 0; t < 4; ++t)
      st4(X2 + ((size_t)t * NTOT + n) * 16 + fq * 4, c[t]);
    float s = 0.f;
#pragma unroll
    for (int t = 0; t < 4; ++t)
#pragma unroll
      for (int r = 0; r < 4; ++r) s += c[t][r];
    s += __shfl_xor(s, 16); s += __shfl_xor(s, 32);
    const float mu = s * (1.f / 64.f);
    float ss = 0.f;
#pragma unroll
    for (int t = 0; t < 4; ++t)
#pragma unroll
      for (int r = 0; r < 4; ++r) { float d = c[t][r] - mu; ss = fmaf(d, d, ss); }
    ss += __shfl_xor(ss, 16); ss += __shfl_xor(ss, 32);
    const float rstd = rsqrtf(ss * (1.f / 64.f) + 1e-5f);
#pragma unroll
    for (int t = 0; t < 4; ++t)
#pragma unroll
      for (int r = 0; r < 4; ++r) {
        const int oc = t * 16 + fq * 4 + r;
        c[t][r] = (c[t][r] - mu) * rstd * n2w[oc] + n2b[oc];
      }
#pragma unroll
    for (int t = 0; t < 4; ++t)
      st4(Y2 + ((size_t)t * NTOT + n) * 16 + fq * 4, c[t]);
  }
}

// ---------------- G4: Hpre (22 blocks) = Win(340x64 padded) * Y2
__global__ __launch_bounds__(256, 2) void g_win(
    const u16* __restrict__ Y2, const float* __restrict__ win,
    u16* __restrict__ hpre)
{
  const int l = threadIdx.x & 63, fr = l & 15, fq = l >> 4;
  const int wv = blockIdx.x * 4 + (threadIdx.x >> 6);
  const int nw = gridDim.x * 4;
  const int half = wv & 1;
  short8 A[11][2];
#pragma unroll
  for (int t = 0; t < 11; ++t)
#pragma unroll
    for (int kh = 0; kh < 2; ++kh) {
      const int col = half * 176 + t * 16 + fr;
      const int row = col < 170 ? col : (col < 176 ? -1 : (col < 346 ? col - 6 : -1));
      A[t][kh] = afrag(win, 64, row, kh * 32 + fq * 8, 64);
    }
  const size_t hof = (size_t)(fq & 1) * 8;
  for (int tile = wv >> 1; tile < 8192; tile += (nw >> 1)) {
    const size_t n = (size_t)tile * 16 + fr;
    const short8 b0 = *reinterpret_cast<const short8*>(
        Y2 + ((size_t)(fq >> 1) * NTOT + n) * 16 + hof);
    const short8 b1 = *reinterpret_cast<const short8*>(
        Y2 + ((size_t)(2 + (fq >> 1)) * NTOT + n) * 16 + hof);
    f32x4 c[11];
#pragma unroll
    for (int t = 0; t < 11; ++t) c[t] = f32x4{0.f, 0.f, 0.f, 0.f};
#pragma unroll
    for (int t = 0; t < 11; ++t) c[t] = mm(A[t][0], b0, c[t]);
#pragma unroll
    for (int t = 0; t < 11; ++t) c[t] = mm(A[t][1], b1, c[t]);
#pragma unroll
    for (int t = 0; t < 11; ++t)
      st4(hpre + ((size_t)(half * 11 + t) * NTOT + n) * 16 + fq * 4, c[t]);
  }
}

// ---------------- G5: out = X2 + Wout(64x170) * Hg (11 blocks)
__global__ __launch_bounds__(256, 2) void g_out(
    const u16* __restrict__ hg, const float* __restrict__ wout,
    const u16* __restrict__ X2, float* __restrict__ out)
{
  const int l = threadIdx.x & 63, fr = l & 15, fq = l >> 4;
  const int wv = blockIdx.x * 4 + (threadIdx.x >> 6);
  const int nw = gridDim.x * 4;
  short8 A[4][6];
#pragma unroll
  for (int t = 0; t < 4; ++t)
#pragma unroll
    for (int kh = 0; kh < 6; ++kh)
      A[t][kh] = afrag(wout, 170, t * 16 + fr, kh * 32 + fq * 8, 170);
  const size_t hof = (size_t)(fq & 1) * 8;
  for (int tile = wv; tile < 8192; tile += nw) {
    const size_t n = (size_t)tile * 16 + fr;
    f32x4 c[4];
#pragma unroll
    for (int t = 0; t < 4; ++t) c[t] = f32x4{0.f, 0.f, 0.f, 0.f};
#pragma unroll
    for (int kh = 0; kh < 6; ++kh) {
      int hb = kh * 2 + (fq >> 1);
      if (hb > 10) hb = 10;  // k>=170 weights are zero; value irrelevant
      const short8 bb = *reinterpret_cast<const short8*>(
          hg + ((size_t)hb * NTOT + n) * 16 + hof);
#pragma unroll
      for (int t = 0; t < 4; ++t) c[t] = mm(A[t][kh], bb, c[t]);
    }
    const int b = (int)(n >> 16);
    const int pix = (int)(n & 65535);
#pragma unroll
    for (int t = 0; t < 4; ++t) {
      const uint2 xv = *reinterpret_cast<const uint2*>(
          X2 + ((size_t)t * NTOT + n) * 16 + fq * 4);
      const u16 h0 = (u16)(xv.x & 0xffff), h1 = (u16)(xv.x >> 16);
      const u16 h2 = (u16)(xv.y & 0xffff), h3 = (u16)(xv.y >> 16);
      const int ocb = b * 64 + t * 16 + fq * 4;
      out[((size_t)(ocb + 0)) * NPB + pix] = c[t][0] + bf2f(h0);
      out[((size_t)(ocb + 1)) * NPB + pix] = c[t][1] + bf2f(h1);
      out[((size_t)(ocb + 2)) * NPB + pix] = c[t][2] + bf2f(h2);
      out[((size_t)(ocb + 3)) * NPB + pix] = c[t][3] + bf2f(h3);
    }
  }
}

extern "C" void kernel_launch(void* const* d_in, const int* in_sizes, int n_in,
                              void* d_out, int out_size, void* d_ws, size_t ws_size,
                              hipStream_t stream)
{
  const float* x     = (const float*)d_in[0];
  const float* n1w   = (const float*)d_in[1];
  const float* n1b   = (const float*)d_in[2];
  const float* temp  = (const float*)d_in[3];
  const float* wqkv  = (const float*)d_in[4];
  const float* wqkvd = (const float*)d_in[5];
  const float* wpo   = (const float*)d_in[6];
  const float* wkv   = (const float*)d_in[7];
  const float* wkvd  = (const float*)d_in[8];
  const float* wpof  = (const float*)d_in[9];
  const float* n2w   = (const float*)d_in[10];
  const float* n2b   = (const float*)d_in[11];
  const float* win   = (const float*)d_in[12];
  const float* wdw   = (const float*)d_in[13];
  const float* wout  = (const float*)d_in[14];
  float* out = (float*)d_out;

  char* ws = (char*)d_ws;
  const size_t offA  = 0;                       // 16.78 MB: Y1 / VFP / Y2
  const size_t offB  = 16777216;                // 50.33 MB: QKVp / VF / Hpre(start)
  const size_t offC  = offB + 50331648;         // 50.33 MB: QKV / Hpre(cont)
  const size_t offHg = offC + 50331648;         // 46.14 MB (11 blocks exactly)
  const size_t offX2 = offHg + 46137344 + 256;  // 16.78 MB
  const size_t offSm = offX2 + 16777216;

  u16* Y1   = (u16*)(ws + offA);
  u16* VFP  = (u16*)(ws + offA);
  u16* Y2   = (u16*)(ws + offA);
  u16* QKVp = (u16*)(ws + offB);
  u16* VF   = (u16*)(ws + offB);
  u16* Hpre = (u16*)(ws + offB);   // 22 blocks span B+C (92.3 MB <= 100.7 MB)
  u16* QKV  = (u16*)(ws + offC);
  u16* Hg   = (u16*)(ws + offHg);
  u16* X2   = (u16*)(ws + offX2);
  float* part = (float*)(ws + offSm);                     // 1,179,648 B
  float* G    = (float*)(ws + offSm + 1179648);           // 8 KB
  float* Sq   = (float*)(ws + offSm + 1179648 + 8192);    // 512 B
  float* Sk   = (float*)(ws + offSm + 1179648 + 8704);    // 512 B
  float* P    = (float*)(ws + offSm + 1179648 + 9216);    // 32 KB
  float* M2   = (float*)(ws + offSm + 1179648 + 41984);   // 32 KB

  k_ln1<<<dim3(NPB / 256, BATCH), 256, 0, stream>>>(x, n1w, n1b, Y1);
  g_qkvp<<<dim3(512), 256, 0, stream>>>(Y1, wqkv, QKVp);
  // dw 192ch: 12 blocks x 2 xchunks, 16 strips, 2 batches
  k_dwr<8, false, 16><<<dim3(24, 16, BATCH), 256, 0, stream>>>(QKVp, QKV, wqkvd, 0);
  k_gram_p<<<dim3(128, 4, BATCH), 256, 0, stream>>>(QKV, part);
  k_gram_red<<<dim3(BATCH * 4), 320, 0, stream>>>(part, G, Sq, Sk);
  k_attn<<<dim3(1), 256, 0, stream>>>(G, Sq, Sk, temp, wpo, wkv, wpof, P, M2);
  g_pv<<<dim3(256, 1, BATCH), 256, 0, stream>>>(QKV, P, VFP);
  // dw 64ch (kv branch, weight rows 64..127): 4 blocks x 2 xchunks, 32 strips
  k_dwr<8, false, 8><<<dim3(8, 32, BATCH), 256, 0, stream>>>(VFP, VF, wkvd, 64);
  g_x2ln<<<dim3(256, 1, BATCH), 256, 0, stream>>>(VF, M2, x, n2w, n2b, X2, Y2);
  g_win<<<dim3(512), 256, 0, stream>>>(Y2, win, Hpre);
  // gated dw 352->176: 11 blocks x 4 xchunks, 16 strips, 2 batches
  k_dwr<4, true, 16><<<dim3(44, 16, BATCH), 256, 0, stream>>>(Hpre, Hg, wdw, 0);
  g_out<<<dim3(512), 256, 0, stream>>>(Hg, wout, X2, out);
}